// Round 8
// baseline (2157.632 us; speedup 1.0000x reference)
//
#include <hip/hip_runtime.h>
#include <math.h>

// GIG_GAT: pheno GEMM + 3x GATConv with CSR-gather aggregation (no feature atomics),
// CSR-gather segment softmax (no atomics), fused bias+relu epilogue. All fp32.
// CSR build: count/scan -> bucketed two-phase fill (write-locality) -> wave-bitonic
// row sort (canonicalizes atomic fill order -> deterministic float accumulation).

#define LRELU_ATT(v) ((v) >= 0.f ? (v) : 0.2f * (v))

// ---------------- GEMM: Y[N,128] = X[N,K] @ W[K,128] + b ----------------
// Block: 256 threads = 16(tx) x 16(ty); thread tile 8x8.
template <int K>
__global__ __launch_bounds__(256)
void gemm_tile(const float* __restrict__ X, const float* __restrict__ W,
               const float* __restrict__ bvec, float* __restrict__ Y, int N)
{
    __shared__ __align__(16) float xt[32][132];   // [k][row], padded stride
    __shared__ __align__(16) float ws[32][132];   // [k][col], padded stride

    const int t  = threadIdx.x;
    const int tx = t & 15, ty = t >> 4;
    const int r0 = blockIdx.x * 128;

    float acc[8][8];
#pragma unroll
    for (int i = 0; i < 8; ++i)
#pragma unroll
        for (int j = 0; j < 8; ++j) acc[i][j] = 0.f;

    const int srow = t >> 3;          // X stage: 32 rows per pass
    const int sk4  = (t & 7) * 4;
    const int wkr  = t >> 5;          // W stage: 8 k-rows per pass
    const int wc4  = (t & 31) * 4;

    for (int kc = 0; kc < K; kc += 32) {
#pragma unroll
        for (int p = 0; p < 4; ++p) {
            const int r  = srow + p * 32;
            const int gr = r0 + r;
            float4 v = make_float4(0.f, 0.f, 0.f, 0.f);
            if (gr < N) v = *reinterpret_cast<const float4*>(&X[(size_t)gr * K + kc + sk4]);
            xt[sk4 + 0][r] = v.x; xt[sk4 + 1][r] = v.y;
            xt[sk4 + 2][r] = v.z; xt[sk4 + 3][r] = v.w;
        }
#pragma unroll
        for (int p = 0; p < 4; ++p) {
            const int k = wkr + p * 8;
            float4 v = *reinterpret_cast<const float4*>(&W[(size_t)(kc + k) * 128 + wc4]);
            *reinterpret_cast<float4*>(&ws[k][wc4]) = v;
        }
        __syncthreads();

#pragma unroll
        for (int k = 0; k < 32; ++k) {
            const float4 a0 = *reinterpret_cast<const float4*>(&xt[k][8 * ty]);
            const float4 a1 = *reinterpret_cast<const float4*>(&xt[k][8 * ty + 4]);
            const float4 b0 = *reinterpret_cast<const float4*>(&ws[k][8 * tx]);
            const float4 b1 = *reinterpret_cast<const float4*>(&ws[k][8 * tx + 4]);
            const float av[8] = {a0.x, a0.y, a0.z, a0.w, a1.x, a1.y, a1.z, a1.w};
            const float bv[8] = {b0.x, b0.y, b0.z, b0.w, b1.x, b1.y, b1.z, b1.w};
#pragma unroll
            for (int i = 0; i < 8; ++i)
#pragma unroll
                for (int j = 0; j < 8; ++j)
                    acc[i][j] = fmaf(av[i], bv[j], acc[i][j]);
        }
        __syncthreads();
    }

    const float4 bb0 = *reinterpret_cast<const float4*>(&bvec[8 * tx]);
    const float4 bb1 = *reinterpret_cast<const float4*>(&bvec[8 * tx + 4]);
#pragma unroll
    for (int i = 0; i < 8; ++i) {
        const int gr = r0 + 8 * ty + i;
        if (gr < N) {
            float4 o0 = make_float4(acc[i][0] + bb0.x, acc[i][1] + bb0.y,
                                    acc[i][2] + bb0.z, acc[i][3] + bb0.w);
            float4 o1 = make_float4(acc[i][4] + bb1.x, acc[i][5] + bb1.y,
                                    acc[i][6] + bb1.z, acc[i][7] + bb1.w);
            *reinterpret_cast<float4*>(&Y[(size_t)gr * 128 + 8 * tx])     = o0;
            *reinterpret_cast<float4*>(&Y[(size_t)gr * 128 + 8 * tx + 4]) = o1;
        }
    }
}

// ---------------- per-node attention dot products ----------------
__global__ __launch_bounds__(256)
void node_dots(const float* __restrict__ H, const float* __restrict__ att,
               float* __restrict__ ai, float* __restrict__ aj, int N)
{
    const int lane = threadIdx.x & 63;
    const int n    = blockIdx.x * 4 + (threadIdx.x >> 6);
    if (n >= N) return;

    const float v0 = H[(size_t)n * 128 + lane];
    const float v1 = H[(size_t)n * 128 + 64 + lane];
    const int hh = lane >> 5, k = lane & 31;

    float si0 = v0 * att[hh * 64 + k];
    float sj0 = v0 * att[hh * 64 + 32 + k];
    float si1 = v1 * att[(2 + hh) * 64 + k];
    float sj1 = v1 * att[(2 + hh) * 64 + 32 + k];

#pragma unroll
    for (int m = 1; m < 32; m <<= 1) {
        si0 += __shfl_xor(si0, m);
        sj0 += __shfl_xor(sj0, m);
        si1 += __shfl_xor(si1, m);
        sj1 += __shfl_xor(sj1, m);
    }
    if ((lane & 31) == 0) {
        const int hA = lane >> 5;
        ai[(size_t)n * 4 + hA]     = si0;
        aj[(size_t)n * 4 + hA]     = sj0;
        ai[(size_t)n * 4 + 2 + hA] = si1;
        aj[(size_t)n * 4 + 2 + hA] = sj1;
    }
}

// ---------------- CSR build ----------------
__global__ __launch_bounds__(256)
void count_deg(const int* __restrict__ ei, int E, int N,
               int* __restrict__ cnt_s, int* __restrict__ cnt_d)
{
    const int e = blockIdx.x * 256 + threadIdx.x;
    if (e >= E + N) return;
    int s, d;
    if (e < E) { s = ei[e]; d = ei[E + e]; } else { s = d = e - E; }
    atomicAdd(&cnt_s[s], 1);
    atomicAdd(&cnt_d[d], 1);
}

__global__ __launch_bounds__(256)
void scan_part(const int* __restrict__ cnt, int* __restrict__ bsum, int n)
{
    __shared__ int sm[256];
    const int i = blockIdx.x * 256 + threadIdx.x;
    sm[threadIdx.x] = (i < n) ? cnt[i] : 0;
    __syncthreads();
    for (int s = 128; s > 0; s >>= 1) {
        if (threadIdx.x < s) sm[threadIdx.x] += sm[threadIdx.x + s];
        __syncthreads();
    }
    if (threadIdx.x == 0) bsum[blockIdx.x] = sm[0];
}

__global__ __launch_bounds__(1024)
void scan_bsums(int* __restrict__ bsum, int nb)
{
    __shared__ int sm[1024];
    const int i = threadIdx.x;
    if (i < nb) sm[i] = bsum[i];
    __syncthreads();
    if (i == 0) {
        int run = 0;
        for (int t = 0; t < nb; ++t) { int v = sm[t]; sm[t] = run; run += v; }
    }
    __syncthreads();
    if (i < nb) bsum[i] = sm[i];
}

__global__ __launch_bounds__(256)
void scan_final(const int* __restrict__ cnt, const int* __restrict__ bsum,
                int* __restrict__ row, int n)
{
    const int i = blockIdx.x * 256 + threadIdx.x;
    const int lane = threadIdx.x & 63, wid = threadIdx.x >> 6;
    int v = (i < n) ? cnt[i] : 0;
    int inc = v;
#pragma unroll
    for (int d = 1; d < 64; d <<= 1) {
        int y = __shfl_up(inc, d);
        if (lane >= d) inc += y;
    }
    __shared__ int wsum[4];
    if (lane == 63) wsum[wid] = inc;
    __syncthreads();
    int wofs = 0;
    for (int w = 0; w < wid; ++w) wofs += wsum[w];
    if (i < n) row[i] = inc - v + wofs + bsum[blockIdx.x];
}

// Phase A: scatter each edge (both directions) into 256-node buckets as a packed
// word ((node&255)<<17 | neighbor). Bucket base in the staging buffer == row[b*256]
// (free from the scan). Tail appends cluster -> ~16 words per 64B line instead of 1.
__global__ __launch_bounds__(256)
void bucket_scatter(const int* __restrict__ ei, int E, int N,
                    const int* __restrict__ row_s, const int* __restrict__ row_d,
                    int* __restrict__ tail_s, int* __restrict__ tail_d,
                    int* __restrict__ bufs, int* __restrict__ bufd)
{
    const int e = blockIdx.x * 256 + threadIdx.x;
    if (e >= E + N) return;
    int s, d;
    if (e < E) { s = ei[e]; d = ei[E + e]; } else { s = d = e - E; }

    const int ps = atomicAdd(&tail_s[s >> 8], 1);
    bufs[row_s[s & ~255] + ps] = ((s & 255) << 17) | d;

    const int pd = atomicAdd(&tail_d[d >> 8], 1);
    bufd[row_d[d & ~255] + pd] = ((d & 255) << 17) | s;
}

// Phase B: per bucket, place staged entries into final CSR rows. All writes land
// in this bucket's ~35KB row region (L2-hot) -> no write-allocate blowup.
__global__ __launch_bounds__(256)
void bucket_fill(const int* __restrict__ row, int* __restrict__ ent,
                 const int* __restrict__ buf, int* __restrict__ fc, int N, int EN)
{
    const int b     = blockIdx.x;
    const int node0 = b << 8;
    const int start = row[node0];
    const int nxt   = node0 + 256;
    const int end   = (nxt >= N) ? EN : row[nxt];
    const int len   = end - start;
    const int chunk = (len + gridDim.y - 1) / gridDim.y;
    const int lo    = start + blockIdx.y * chunk;
    const int hi    = min(lo + chunk, end);
    for (int i = lo + threadIdx.x; i < hi; i += 256) {
        const unsigned w = (unsigned)buf[i];
        const int n = node0 | (int)(w >> 17);
        const int v = (int)(w & 0x1FFFFu);
        ent[row[n] + atomicAdd(&fc[n], 1)] = v;
    }
}

// Canonicalize each row ascending -> deterministic accumulation order everywhere.
// One wave per node: 64-lane shfl_xor bitonic network (deg<=64); fallback for more.
__global__ __launch_bounds__(256)
void sort_rows_wave(const int* __restrict__ row, int* __restrict__ ent, int N, int EN)
{
    const int lane = threadIdx.x & 63;
    const int n    = blockIdx.x * 4 + (threadIdx.x >> 6);
    if (n >= N) return;
    const int lo  = row[n];
    const int hi  = (n == N - 1) ? EN : row[n + 1];
    const int deg = hi - lo;

    if (deg > 64) {                       // safety fallback (unexpected for this graph)
        if (lane == 0) {
            for (int i = lo + 1; i < hi; ++i) {
                int v = ent[i], j = i - 1;
                while (j >= lo && ent[j] > v) { ent[j + 1] = ent[j]; --j; }
                ent[j + 1] = v;
            }
        }
        return;
    }

    int v = (lane < deg) ? ent[lo + lane] : 0x7FFFFFFF;
#pragma unroll
    for (int k = 2; k <= 64; k <<= 1) {
#pragma unroll
        for (int j = k >> 1; j > 0; j >>= 1) {
            const int w  = __shfl_xor(v, j);
            const bool up   = ((lane & k) == 0);
            const bool lowr = ((lane & j) == 0);
            v = (lowr == up) ? min(v, w) : max(v, w);
        }
    }
    if (lane < deg) ent[lo + lane] = v;
}

// ---------------- segment softmax grouped by src (gather, no atomics) ----------------
__global__ __launch_bounds__(256)
void softmax_src(const int* __restrict__ row_s, const int* __restrict__ ent_s,
                 const float* __restrict__ ai, const float* __restrict__ aj,
                 float* __restrict__ amaxF, float* __restrict__ rden,
                 int N, int EN)
{
    const int lane = threadIdx.x & 63;
    const int n    = blockIdx.x * 4 + (threadIdx.x >> 6);
    if (n >= N) return;
    const int row = row_s[n];
    const int end = (n == N - 1) ? EN : row_s[n + 1];
    const int slot = lane & 15, h = lane >> 4;
    const float ajh = aj[(size_t)n * 4 + h];

    float m = -INFINITY;
    for (int t = row + slot; t < end; t += 16) {
        const int d = ent_s[t];
        const float a = LRELU_ATT(ai[(size_t)d * 4 + h] + ajh);
        m = fmaxf(m, a);
    }
#pragma unroll
    for (int mm = 1; mm < 16; mm <<= 1) m = fmaxf(m, __shfl_xor(m, mm));

    float ssum = 0.f;
    for (int t = row + slot; t < end; t += 16) {
        const int d = ent_s[t];
        const float a = LRELU_ATT(ai[(size_t)d * 4 + h] + ajh);
        ssum += __expf(a - m);
    }
#pragma unroll
    for (int mm = 1; mm < 16; mm <<= 1) ssum += __shfl_xor(ssum, mm);

    if (slot == 0) {
        amaxF[(size_t)n * 4 + h] = m;
        rden[(size_t)n * 4 + h]  = 1.f / (ssum + 1e-16f);
    }
}

// ---------------- aggregation by dst (gather, no atomics), fused bias+relu ----------------
__global__ __launch_bounds__(256)
void aggregate_dst(const int* __restrict__ row_d, const int* __restrict__ ent_d,
                   const float* __restrict__ ai, const float* __restrict__ aj,
                   const float* __restrict__ amaxF, const float* __restrict__ rden,
                   const float* __restrict__ H, const float* __restrict__ bias,
                   float* __restrict__ OUT, int N, int EN)
{
    const int lane = threadIdx.x & 63;
    const int n    = blockIdx.x * 4 + (threadIdx.x >> 6);
    if (n >= N) return;
    const int row = row_d[n];
    const int end = (n == N - 1) ? EN : row_d[n + 1];
    const int h   = lane >> 4;
    const float aih = ai[(size_t)n * 4 + h];

    float accx = 0.f, accy = 0.f;
    for (int t = row; t < end; ++t) {
        const int s = ent_d[t];
        const float a    = LRELU_ATT(aih + aj[(size_t)s * 4 + h]);
        const float coef = __expf(a - amaxF[(size_t)s * 4 + h]) * rden[(size_t)s * 4 + h];
        const float2 hv  = *reinterpret_cast<const float2*>(&H[(size_t)s * 128 + lane * 2]);
        accx = fmaf(hv.x, coef, accx);
        accy = fmaf(hv.y, coef, accy);
    }
    const float2 bv = *reinterpret_cast<const float2*>(&bias[lane * 2]);
    OUT[(size_t)n * 128 + lane * 2]     = fmaxf(accx + bv.x, 0.f);
    OUT[(size_t)n * 128 + lane * 2 + 1] = fmaxf(accy + bv.y, 0.f);
}

// ---------------- output head ----------------
__global__ __launch_bounds__(256)
void out_kernel(const float* __restrict__ G, const float* __restrict__ oW,
                float* __restrict__ out3, float* __restrict__ ypredF, int N)
{
    __shared__ float w[384];
    for (int i = threadIdx.x; i < 384; i += 256) w[i] = oW[i];
    __syncthreads();
    const int n = blockIdx.x * 256 + threadIdx.x;
    if (n >= N) return;
    const float* g = G + (size_t)n * 128;
    float a0 = 0.f, a1 = 0.f, a2 = 0.f;
    for (int k = 0; k < 128; k += 4) {
        float4 gv = *reinterpret_cast<const float4*>(&g[k]);
        a0 = fmaf(gv.x, w[(k+0)*3+0], a0); a1 = fmaf(gv.x, w[(k+0)*3+1], a1); a2 = fmaf(gv.x, w[(k+0)*3+2], a2);
        a0 = fmaf(gv.y, w[(k+1)*3+0], a0); a1 = fmaf(gv.y, w[(k+1)*3+1], a1); a2 = fmaf(gv.y, w[(k+1)*3+2], a2);
        a0 = fmaf(gv.z, w[(k+2)*3+0], a0); a1 = fmaf(gv.z, w[(k+2)*3+1], a1); a2 = fmaf(gv.z, w[(k+2)*3+2], a2);
        a0 = fmaf(gv.w, w[(k+3)*3+0], a0); a1 = fmaf(gv.w, w[(k+3)*3+1], a1); a2 = fmaf(gv.w, w[(k+3)*3+2], a2);
    }
    out3[(size_t)n * 3 + 0] = a0;
    out3[(size_t)n * 3 + 1] = a1;
    out3[(size_t)n * 3 + 2] = a2;
    int idx = 0; float best = a0;
    if (a1 > best) { best = a1; idx = 1; }
    if (a2 > best) { best = a2; idx = 2; }
    ypredF[n] = (float)idx;
}

__global__ __launch_bounds__(256)
void gather_kernel(const int* __restrict__ nix, const float* __restrict__ out3,
                   const float* __restrict__ ypredF, float* __restrict__ nodeOut,
                   float* __restrict__ ynode, int M)
{
    const int i = blockIdx.x * 256 + threadIdx.x;
    if (i >= M) return;
    const int n = nix[i];
    nodeOut[(size_t)i * 3 + 0] = out3[(size_t)n * 3 + 0];
    nodeOut[(size_t)i * 3 + 1] = out3[(size_t)n * 3 + 1];
    nodeOut[(size_t)i * 3 + 2] = out3[(size_t)n * 3 + 2];
    ynode[i] = ypredF[n];
}

extern "C" void kernel_launch(void* const* d_in, const int* in_sizes, int n_in,
                              void* d_out, int out_size, void* d_ws, size_t ws_size,
                              hipStream_t stream)
{
    const float* x      = (const float*)d_in[0];
    const int*   ei     = (const int*)d_in[1];
    const int*   nodeix = (const int*)d_in[2];
    const float* phW    = (const float*)d_in[3];
    const float* phb    = (const float*)d_in[4];
    const float* Wl[3]   = {(const float*)d_in[5],  (const float*)d_in[9],  (const float*)d_in[13]};
    const float* bl[3]   = {(const float*)d_in[6],  (const float*)d_in[10], (const float*)d_in[14]};
    const float* attl[3] = {(const float*)d_in[7],  (const float*)d_in[11], (const float*)d_in[15]};
    const float* bsl[3]  = {(const float*)d_in[8],  (const float*)d_in[12], (const float*)d_in[16]};
    const float* outW    = (const float*)d_in[17];

    const int N  = in_sizes[0] / 256;
    const int E  = in_sizes[1] / 2;
    const int M  = in_sizes[2];
    const int EN = E + N;
    const int NB = (N + 255) >> 8;    // 256-node buckets

    // ---- workspace layout ----
    float* P     = (float*)d_ws;                    // N*128
    float* Q     = P + (size_t)N * 128;             // N*128 (aliased as CSR staging below)
    float* ai    = Q + (size_t)N * 128;             // N*4
    float* aj    = ai + (size_t)N * 4;              // N*4
    float* amaxF = aj + (size_t)N * 4;              // N*4
    float* rden  = amaxF + (size_t)N * 4;           // N*4
    float* out3  = rden + (size_t)N * 4;            // N*3
    int* row_s   = (int*)(out3 + (size_t)N * 3);    // N
    int* row_d   = row_s + N;                       // N
    int* cnt_s   = row_d + N;                       // N (histogram, reused as fill ctr)
    int* cnt_d   = cnt_s + N;                       // N
    int* tail_s  = cnt_d + N;                       // NB (bucket tails)
    int* tail_d  = tail_s + NB;                     // NB
    int* bsum_s  = tail_d + NB;                     // 1024
    int* bsum_d  = bsum_s + 1024;                   // 1024
    int* ent_s   = bsum_d + 1024;                   // EN
    int* ent_d   = ent_s + (size_t)EN;              // EN

    // Phase-A staging buffers alias Q (unused until the first GEMM): 2*EN ints <= N*128 floats
    int* bufA_s = (int*)Q;
    int* bufA_d = bufA_s + (size_t)EN;

    // ---- d_out layout: x_embed[N*128] node_output[M*3] ypred[N] y_nodepred[M]
    float* o_embed   = (float*)d_out;
    float* o_nodeout = o_embed + (size_t)N * 128;
    float* o_ypred   = o_nodeout + (size_t)M * 3;
    float* o_ynode   = o_ypred + N;

    const int nb = (N + 255) / 256;
    const int ng = (N + 127) / 128;   // GEMM grid

    // ---- CSR build (once; reused by all 3 layers) ----
    hipMemsetAsync(cnt_s, 0, ((size_t)2 * N + 2 * NB) * sizeof(int), stream);  // cnt_s,cnt_d,tails
    count_deg<<<(EN + 255) / 256, 256, 0, stream>>>(ei, E, N, cnt_s, cnt_d);
    scan_part<<<nb, 256, 0, stream>>>(cnt_s, bsum_s, N);
    scan_part<<<nb, 256, 0, stream>>>(cnt_d, bsum_d, N);
    scan_bsums<<<1, 1024, 0, stream>>>(bsum_s, nb);
    scan_bsums<<<1, 1024, 0, stream>>>(bsum_d, nb);
    scan_final<<<nb, 256, 0, stream>>>(cnt_s, bsum_s, row_s, N);
    scan_final<<<nb, 256, 0, stream>>>(cnt_d, bsum_d, row_d, N);
    // Phase A: bucket scatter (tail-clustered writes)
    bucket_scatter<<<(EN + 255) / 256, 256, 0, stream>>>(ei, E, N, row_s, row_d,
                                                         tail_s, tail_d, bufA_s, bufA_d);
    // Phase B: place into final rows (writes confined to hot bucket regions)
    hipMemsetAsync(cnt_s, 0, (size_t)2 * N * sizeof(int), stream);
    bucket_fill<<<dim3(NB, 8), 256, 0, stream>>>(row_s, ent_s, bufA_s, cnt_s, N, EN);
    bucket_fill<<<dim3(NB, 8), 256, 0, stream>>>(row_d, ent_d, bufA_d, cnt_d, N, EN);
    // canonicalize row order -> deterministic float accumulation on every call
    sort_rows_wave<<<(N + 3) / 4, 256, 0, stream>>>(row_s, ent_s, N, EN);
    sort_rows_wave<<<(N + 3) / 4, 256, 0, stream>>>(row_d, ent_d, N, EN);

    // ---- pheno transform: P = x @ phW + phb ----
    gemm_tile<256><<<ng, 256, 0, stream>>>(x, phW, phb, P, N);

    // ---- 3 GAT layers ----
    for (int l = 0; l < 3; ++l) {
        float* tgt = (l == 2) ? o_embed : P;   // layer 3 writes x_embed directly
        gemm_tile<128><<<ng, 256, 0, stream>>>(P, Wl[l], bl[l], Q, N);
        node_dots<<<(N + 3) / 4, 256, 0, stream>>>(Q, attl[l], ai, aj, N);
        softmax_src<<<(N + 3) / 4, 256, 0, stream>>>(row_s, ent_s, ai, aj, amaxF, rden, N, EN);
        aggregate_dst<<<(N + 3) / 4, 256, 0, stream>>>(row_d, ent_d, ai, aj, amaxF, rden,
                                                       Q, bsl[l], tgt, N, EN);
    }

    out_kernel<<<(N + 255) / 256, 256, 0, stream>>>(o_embed, outW, out3, o_ypred, N);
    gather_kernel<<<(M + 255) / 256, 256, 0, stream>>>(nodeix, out3, o_ypred, o_nodeout, o_ynode, M);
}

// Round 9
// 1381.499 us; speedup vs baseline: 1.5618x; 1.5618x over previous
//
#include <hip/hip_runtime.h>
#include <math.h>

// GIG_GAT: pheno GEMM + 3x GATConv with CSR-gather aggregation (no feature atomics),
// CSR-gather segment softmax (no atomics), fused bias+relu epilogue. All fp32.
// CSR build: count/scan -> LDS-binned radix partition (per-WG chunk reservation so
// adjacent staging slots are written by ONE CU -> no write-allocate blowup, no deep
// same-address atomic chains) -> per-bucket place -> wave-bitonic row sort
// (canonicalizes atomic fill order -> deterministic float accumulation everywhere).

#define LRELU_ATT(v) ((v) >= 0.f ? (v) : 0.2f * (v))
#define SCAT_CHUNK 8192

// ---------------- GEMM: Y[N,128] = X[N,K] @ W[K,128] + b ----------------
// Block: 256 threads = 16(tx) x 16(ty); thread tile 8x8.
template <int K>
__global__ __launch_bounds__(256)
void gemm_tile(const float* __restrict__ X, const float* __restrict__ W,
               const float* __restrict__ bvec, float* __restrict__ Y, int N)
{
    __shared__ __align__(16) float xt[32][132];   // [k][row], padded stride
    __shared__ __align__(16) float ws[32][132];   // [k][col], padded stride

    const int t  = threadIdx.x;
    const int tx = t & 15, ty = t >> 4;
    const int r0 = blockIdx.x * 128;

    float acc[8][8];
#pragma unroll
    for (int i = 0; i < 8; ++i)
#pragma unroll
        for (int j = 0; j < 8; ++j) acc[i][j] = 0.f;

    const int srow = t >> 3;          // X stage: 32 rows per pass
    const int sk4  = (t & 7) * 4;
    const int wkr  = t >> 5;          // W stage: 8 k-rows per pass
    const int wc4  = (t & 31) * 4;

    for (int kc = 0; kc < K; kc += 32) {
#pragma unroll
        for (int p = 0; p < 4; ++p) {
            const int r  = srow + p * 32;
            const int gr = r0 + r;
            float4 v = make_float4(0.f, 0.f, 0.f, 0.f);
            if (gr < N) v = *reinterpret_cast<const float4*>(&X[(size_t)gr * K + kc + sk4]);
            xt[sk4 + 0][r] = v.x; xt[sk4 + 1][r] = v.y;
            xt[sk4 + 2][r] = v.z; xt[sk4 + 3][r] = v.w;
        }
#pragma unroll
        for (int p = 0; p < 4; ++p) {
            const int k = wkr + p * 8;
            float4 v = *reinterpret_cast<const float4*>(&W[(size_t)(kc + k) * 128 + wc4]);
            *reinterpret_cast<float4*>(&ws[k][wc4]) = v;
        }
        __syncthreads();

#pragma unroll
        for (int k = 0; k < 32; ++k) {
            const float4 a0 = *reinterpret_cast<const float4*>(&xt[k][8 * ty]);
            const float4 a1 = *reinterpret_cast<const float4*>(&xt[k][8 * ty + 4]);
            const float4 b0 = *reinterpret_cast<const float4*>(&ws[k][8 * tx]);
            const float4 b1 = *reinterpret_cast<const float4*>(&ws[k][8 * tx + 4]);
            const float av[8] = {a0.x, a0.y, a0.z, a0.w, a1.x, a1.y, a1.z, a1.w};
            const float bv[8] = {b0.x, b0.y, b0.z, b0.w, b1.x, b1.y, b1.z, b1.w};
#pragma unroll
            for (int i = 0; i < 8; ++i)
#pragma unroll
                for (int j = 0; j < 8; ++j)
                    acc[i][j] = fmaf(av[i], bv[j], acc[i][j]);
        }
        __syncthreads();
    }

    const float4 bb0 = *reinterpret_cast<const float4*>(&bvec[8 * tx]);
    const float4 bb1 = *reinterpret_cast<const float4*>(&bvec[8 * tx + 4]);
#pragma unroll
    for (int i = 0; i < 8; ++i) {
        const int gr = r0 + 8 * ty + i;
        if (gr < N) {
            float4 o0 = make_float4(acc[i][0] + bb0.x, acc[i][1] + bb0.y,
                                    acc[i][2] + bb0.z, acc[i][3] + bb0.w);
            float4 o1 = make_float4(acc[i][4] + bb1.x, acc[i][5] + bb1.y,
                                    acc[i][6] + bb1.z, acc[i][7] + bb1.w);
            *reinterpret_cast<float4*>(&Y[(size_t)gr * 128 + 8 * tx])     = o0;
            *reinterpret_cast<float4*>(&Y[(size_t)gr * 128 + 8 * tx + 4]) = o1;
        }
    }
}

// ---------------- per-node attention dot products ----------------
__global__ __launch_bounds__(256)
void node_dots(const float* __restrict__ H, const float* __restrict__ att,
               float* __restrict__ ai, float* __restrict__ aj, int N)
{
    const int lane = threadIdx.x & 63;
    const int n    = blockIdx.x * 4 + (threadIdx.x >> 6);
    if (n >= N) return;

    const float v0 = H[(size_t)n * 128 + lane];
    const float v1 = H[(size_t)n * 128 + 64 + lane];
    const int hh = lane >> 5, k = lane & 31;

    float si0 = v0 * att[hh * 64 + k];
    float sj0 = v0 * att[hh * 64 + 32 + k];
    float si1 = v1 * att[(2 + hh) * 64 + k];
    float sj1 = v1 * att[(2 + hh) * 64 + 32 + k];

#pragma unroll
    for (int m = 1; m < 32; m <<= 1) {
        si0 += __shfl_xor(si0, m);
        sj0 += __shfl_xor(sj0, m);
        si1 += __shfl_xor(si1, m);
        sj1 += __shfl_xor(sj1, m);
    }
    if ((lane & 31) == 0) {
        const int hA = lane >> 5;
        ai[(size_t)n * 4 + hA]     = si0;
        aj[(size_t)n * 4 + hA]     = sj0;
        ai[(size_t)n * 4 + 2 + hA] = si1;
        aj[(size_t)n * 4 + 2 + hA] = sj1;
    }
}

// ---------------- CSR build ----------------
__global__ __launch_bounds__(256)
void count_deg(const int* __restrict__ ei, int E, int N,
               int* __restrict__ cnt_s, int* __restrict__ cnt_d)
{
    const int e = blockIdx.x * 256 + threadIdx.x;
    if (e >= E + N) return;
    int s, d;
    if (e < E) { s = ei[e]; d = ei[E + e]; } else { s = d = e - E; }
    atomicAdd(&cnt_s[s], 1);
    atomicAdd(&cnt_d[d], 1);
}

__global__ __launch_bounds__(256)
void scan_part(const int* __restrict__ cnt, int* __restrict__ bsum, int n)
{
    __shared__ int sm[256];
    const int i = blockIdx.x * 256 + threadIdx.x;
    sm[threadIdx.x] = (i < n) ? cnt[i] : 0;
    __syncthreads();
    for (int s = 128; s > 0; s >>= 1) {
        if (threadIdx.x < s) sm[threadIdx.x] += sm[threadIdx.x + s];
        __syncthreads();
    }
    if (threadIdx.x == 0) bsum[blockIdx.x] = sm[0];
}

__global__ __launch_bounds__(1024)
void scan_bsums(int* __restrict__ bsum, int nb)
{
    __shared__ int sm[1024];
    const int i = threadIdx.x;
    if (i < nb) sm[i] = bsum[i];
    __syncthreads();
    if (i == 0) {
        int run = 0;
        for (int t = 0; t < nb; ++t) { int v = sm[t]; sm[t] = run; run += v; }
    }
    __syncthreads();
    if (i < nb) bsum[i] = sm[i];
}

__global__ __launch_bounds__(256)
void scan_final(const int* __restrict__ cnt, const int* __restrict__ bsum,
                int* __restrict__ row, int n)
{
    const int i = blockIdx.x * 256 + threadIdx.x;
    const int lane = threadIdx.x & 63, wid = threadIdx.x >> 6;
    int v = (i < n) ? cnt[i] : 0;
    int inc = v;
#pragma unroll
    for (int d = 1; d < 64; d <<= 1) {
        int y = __shfl_up(inc, d);
        if (lane >= d) inc += y;
    }
    __shared__ int wsum[4];
    if (lane == 63) wsum[wid] = inc;
    __syncthreads();
    int wofs = 0;
    for (int w = 0; w < wid; ++w) wofs += wsum[w];
    if (i < n) row[i] = inc - v + wofs + bsum[blockIdx.x];
}

// Bucket b (256 nodes) starts at row[b<<8] in the staging/ent arrays.
__global__ __launch_bounds__(256)
void init_tails(const int* __restrict__ row_s, const int* __restrict__ row_d,
                int* __restrict__ tail_s, int* __restrict__ tail_d, int NB)
{
    const int b = blockIdx.x * 256 + threadIdx.x;
    if (b >= NB) return;
    tail_s[b] = row_s[b << 8];
    tail_d[b] = row_d[b << 8];
}

// LDS-binned radix partition: each WG takes SCAT_CHUNK edges, counts buckets in
// LDS, reserves a contiguous chunk per bucket with ONE global atomic, then places
// packed words ((node&255)<<17 | neighbor) into its reserved (CU-local) chunk.
// Adjacent staging slots are written by the same CU -> full-line writes, no
// cross-XCD line ping-pong, ~160K global atomics instead of 3.4M.
__global__ __launch_bounds__(256)
void radix_scatter(const int* __restrict__ ei, int E, int N, int NB,
                   int* __restrict__ tail_s, int* __restrict__ tail_d,
                   int* __restrict__ bufs, int* __restrict__ bufd)
{
    __shared__ int cnt_s[512], cnt_d[512];
    const int base_e = blockIdx.x * SCAT_CHUNK;
    const int end_e  = min(base_e + SCAT_CHUNK, E + N);

    for (int i = threadIdx.x; i < NB; i += 256) { cnt_s[i] = 0; cnt_d[i] = 0; }
    __syncthreads();

    // pass 1: count bucket occupancy for this chunk
    for (int e = base_e + threadIdx.x; e < end_e; e += 256) {
        int s, d;
        if (e < E) { s = ei[e]; d = ei[E + e]; } else { s = d = e - E; }
        atomicAdd(&cnt_s[s >> 8], 1);
        atomicAdd(&cnt_d[d >> 8], 1);
    }
    __syncthreads();

    // reserve contiguous chunks; cnt becomes the running global position
    for (int b = threadIdx.x; b < NB; b += 256) {
        const int c0 = cnt_s[b];
        cnt_s[b] = c0 ? atomicAdd(&tail_s[b], c0) : 0;
        const int c1 = cnt_d[b];
        cnt_d[b] = c1 ? atomicAdd(&tail_d[b], c1) : 0;
    }
    __syncthreads();

    // pass 2: place into reserved chunks (writes CU-local and contiguous)
    for (int e = base_e + threadIdx.x; e < end_e; e += 256) {
        int s, d;
        if (e < E) { s = ei[e]; d = ei[E + e]; } else { s = d = e - E; }
        const int ps = atomicAdd(&cnt_s[s >> 8], 1);
        bufs[ps] = ((s & 255) << 17) | d;
        const int pd = atomicAdd(&cnt_d[d >> 8], 1);
        bufd[pd] = ((d & 255) << 17) | s;
    }
}

// One WG per bucket (grid.y selects direction): place staged words into final CSR
// rows. Per-node slot counters live in LDS; all writes confined to this bucket's
// ~17KB row region and issued by one CU.
__global__ __launch_bounds__(256)
void bucket_place(const int* __restrict__ row_s, int* __restrict__ ent_s, const int* __restrict__ bufs,
                  const int* __restrict__ row_d, int* __restrict__ ent_d, const int* __restrict__ bufd,
                  int N, int NB, int EN)
{
    const int* __restrict__ row = (blockIdx.y == 0) ? row_s : row_d;
    int*       __restrict__ ent = (blockIdx.y == 0) ? ent_s : ent_d;
    const int* __restrict__ buf = (blockIdx.y == 0) ? bufs  : bufd;

    __shared__ int fc[256];
    const int node0 = blockIdx.x << 8;
    const int start = row[node0];
    const int nxt   = node0 + 256;
    const int end   = (nxt >= N) ? EN : row[nxt];

    fc[threadIdx.x] = 0;
    __syncthreads();

    for (int i = start + threadIdx.x; i < end; i += 256) {
        const unsigned w  = (unsigned)buf[i];
        const int loc  = (int)(w >> 17);
        const int slot = atomicAdd(&fc[loc], 1);
        ent[row[node0 | loc] + slot] = (int)(w & 0x1FFFFu);
    }
}

// Canonicalize each row ascending -> deterministic accumulation order everywhere.
// One wave per node: 64-lane shfl_xor bitonic network (deg<=64); fallback for more.
__global__ __launch_bounds__(256)
void sort_rows_wave(const int* __restrict__ row, int* __restrict__ ent, int N, int EN)
{
    const int lane = threadIdx.x & 63;
    const int n    = blockIdx.x * 4 + (threadIdx.x >> 6);
    if (n >= N) return;
    const int lo  = row[n];
    const int hi  = (n == N - 1) ? EN : row[n + 1];
    const int deg = hi - lo;

    if (deg > 64) {                       // safety fallback (unexpected for this graph)
        if (lane == 0) {
            for (int i = lo + 1; i < hi; ++i) {
                int v = ent[i], j = i - 1;
                while (j >= lo && ent[j] > v) { ent[j + 1] = ent[j]; --j; }
                ent[j + 1] = v;
            }
        }
        return;
    }

    int v = (lane < deg) ? ent[lo + lane] : 0x7FFFFFFF;
#pragma unroll
    for (int k = 2; k <= 64; k <<= 1) {
#pragma unroll
        for (int j = k >> 1; j > 0; j >>= 1) {
            const int w  = __shfl_xor(v, j);
            const bool up   = ((lane & k) == 0);
            const bool lowr = ((lane & j) == 0);
            v = (lowr == up) ? min(v, w) : max(v, w);
        }
    }
    if (lane < deg) ent[lo + lane] = v;
}

// ---------------- segment softmax grouped by src (gather, no atomics) ----------------
__global__ __launch_bounds__(256)
void softmax_src(const int* __restrict__ row_s, const int* __restrict__ ent_s,
                 const float* __restrict__ ai, const float* __restrict__ aj,
                 float* __restrict__ amaxF, float* __restrict__ rden,
                 int N, int EN)
{
    const int lane = threadIdx.x & 63;
    const int n    = blockIdx.x * 4 + (threadIdx.x >> 6);
    if (n >= N) return;
    const int row = row_s[n];
    const int end = (n == N - 1) ? EN : row_s[n + 1];
    const int slot = lane & 15, h = lane >> 4;
    const float ajh = aj[(size_t)n * 4 + h];

    float m = -INFINITY;
    for (int t = row + slot; t < end; t += 16) {
        const int d = ent_s[t];
        const float a = LRELU_ATT(ai[(size_t)d * 4 + h] + ajh);
        m = fmaxf(m, a);
    }
#pragma unroll
    for (int mm = 1; mm < 16; mm <<= 1) m = fmaxf(m, __shfl_xor(m, mm));

    float ssum = 0.f;
    for (int t = row + slot; t < end; t += 16) {
        const int d = ent_s[t];
        const float a = LRELU_ATT(ai[(size_t)d * 4 + h] + ajh);
        ssum += __expf(a - m);
    }
#pragma unroll
    for (int mm = 1; mm < 16; mm <<= 1) ssum += __shfl_xor(ssum, mm);

    if (slot == 0) {
        amaxF[(size_t)n * 4 + h] = m;
        rden[(size_t)n * 4 + h]  = 1.f / (ssum + 1e-16f);
    }
}

// ---------------- aggregation by dst (gather, no atomics), fused bias+relu ----------------
__global__ __launch_bounds__(256)
void aggregate_dst(const int* __restrict__ row_d, const int* __restrict__ ent_d,
                   const float* __restrict__ ai, const float* __restrict__ aj,
                   const float* __restrict__ amaxF, const float* __restrict__ rden,
                   const float* __restrict__ H, const float* __restrict__ bias,
                   float* __restrict__ OUT, int N, int EN)
{
    const int lane = threadIdx.x & 63;
    const int n    = blockIdx.x * 4 + (threadIdx.x >> 6);
    if (n >= N) return;
    const int row = row_d[n];
    const int end = (n == N - 1) ? EN : row_d[n + 1];
    const int h   = lane >> 4;
    const float aih = ai[(size_t)n * 4 + h];

    float accx = 0.f, accy = 0.f;
    for (int t = row; t < end; ++t) {
        const int s = ent_d[t];
        const float a    = LRELU_ATT(aih + aj[(size_t)s * 4 + h]);
        const float coef = __expf(a - amaxF[(size_t)s * 4 + h]) * rden[(size_t)s * 4 + h];
        const float2 hv  = *reinterpret_cast<const float2*>(&H[(size_t)s * 128 + lane * 2]);
        accx = fmaf(hv.x, coef, accx);
        accy = fmaf(hv.y, coef, accy);
    }
    const float2 bv = *reinterpret_cast<const float2*>(&bias[lane * 2]);
    OUT[(size_t)n * 128 + lane * 2]     = fmaxf(accx + bv.x, 0.f);
    OUT[(size_t)n * 128 + lane * 2 + 1] = fmaxf(accy + bv.y, 0.f);
}

// ---------------- output head ----------------
__global__ __launch_bounds__(256)
void out_kernel(const float* __restrict__ G, const float* __restrict__ oW,
                float* __restrict__ out3, float* __restrict__ ypredF, int N)
{
    __shared__ float w[384];
    for (int i = threadIdx.x; i < 384; i += 256) w[i] = oW[i];
    __syncthreads();
    const int n = blockIdx.x * 256 + threadIdx.x;
    if (n >= N) return;
    const float* g = G + (size_t)n * 128;
    float a0 = 0.f, a1 = 0.f, a2 = 0.f;
    for (int k = 0; k < 128; k += 4) {
        float4 gv = *reinterpret_cast<const float4*>(&g[k]);
        a0 = fmaf(gv.x, w[(k+0)*3+0], a0); a1 = fmaf(gv.x, w[(k+0)*3+1], a1); a2 = fmaf(gv.x, w[(k+0)*3+2], a2);
        a0 = fmaf(gv.y, w[(k+1)*3+0], a0); a1 = fmaf(gv.y, w[(k+1)*3+1], a1); a2 = fmaf(gv.y, w[(k+1)*3+2], a2);
        a0 = fmaf(gv.z, w[(k+2)*3+0], a0); a1 = fmaf(gv.z, w[(k+2)*3+1], a1); a2 = fmaf(gv.z, w[(k+2)*3+2], a2);
        a0 = fmaf(gv.w, w[(k+3)*3+0], a0); a1 = fmaf(gv.w, w[(k+3)*3+1], a1); a2 = fmaf(gv.w, w[(k+3)*3+2], a2);
    }
    out3[(size_t)n * 3 + 0] = a0;
    out3[(size_t)n * 3 + 1] = a1;
    out3[(size_t)n * 3 + 2] = a2;
    int idx = 0; float best = a0;
    if (a1 > best) { best = a1; idx = 1; }
    if (a2 > best) { best = a2; idx = 2; }
    ypredF[n] = (float)idx;
}

__global__ __launch_bounds__(256)
void gather_kernel(const int* __restrict__ nix, const float* __restrict__ out3,
                   const float* __restrict__ ypredF, float* __restrict__ nodeOut,
                   float* __restrict__ ynode, int M)
{
    const int i = blockIdx.x * 256 + threadIdx.x;
    if (i >= M) return;
    const int n = nix[i];
    nodeOut[(size_t)i * 3 + 0] = out3[(size_t)n * 3 + 0];
    nodeOut[(size_t)i * 3 + 1] = out3[(size_t)n * 3 + 1];
    nodeOut[(size_t)i * 3 + 2] = out3[(size_t)n * 3 + 2];
    ynode[i] = ypredF[n];
}

extern "C" void kernel_launch(void* const* d_in, const int* in_sizes, int n_in,
                              void* d_out, int out_size, void* d_ws, size_t ws_size,
                              hipStream_t stream)
{
    const float* x      = (const float*)d_in[0];
    const int*   ei     = (const int*)d_in[1];
    const int*   nodeix = (const int*)d_in[2];
    const float* phW    = (const float*)d_in[3];
    const float* phb    = (const float*)d_in[4];
    const float* Wl[3]   = {(const float*)d_in[5],  (const float*)d_in[9],  (const float*)d_in[13]};
    const float* bl[3]   = {(const float*)d_in[6],  (const float*)d_in[10], (const float*)d_in[14]};
    const float* attl[3] = {(const float*)d_in[7],  (const float*)d_in[11], (const float*)d_in[15]};
    const float* bsl[3]  = {(const float*)d_in[8],  (const float*)d_in[12], (const float*)d_in[16]};
    const float* outW    = (const float*)d_in[17];

    const int N  = in_sizes[0] / 256;
    const int E  = in_sizes[1] / 2;
    const int M  = in_sizes[2];
    const int EN = E + N;
    const int NB = (N + 255) >> 8;    // 256-node buckets (<=512 for N<=131072)

    // ---- workspace layout ----
    float* P     = (float*)d_ws;                    // N*128
    float* Q     = P + (size_t)N * 128;             // N*128 (aliased as CSR staging below)
    float* ai    = Q + (size_t)N * 128;             // N*4
    float* aj    = ai + (size_t)N * 4;              // N*4
    float* amaxF = aj + (size_t)N * 4;              // N*4
    float* rden  = amaxF + (size_t)N * 4;           // N*4
    float* out3  = rden + (size_t)N * 4;            // N*3
    int* row_s   = (int*)(out3 + (size_t)N * 3);    // N
    int* row_d   = row_s + N;                       // N
    int* cnt_s   = row_d + N;                       // N (degree histogram)
    int* cnt_d   = cnt_s + N;                       // N
    int* tail_s  = cnt_d + N;                       // NB (bucket tails)
    int* tail_d  = tail_s + NB;                     // NB
    int* bsum_s  = tail_d + NB;                     // 1024
    int* bsum_d  = bsum_s + 1024;                   // 1024
    int* ent_s   = bsum_d + 1024;                   // EN
    int* ent_d   = ent_s + (size_t)EN;              // EN

    // staging buffers alias Q (unused until the first GEMM): 2*EN ints <= N*128 floats
    int* bufA_s = (int*)Q;
    int* bufA_d = bufA_s + (size_t)EN;

    // ---- d_out layout: x_embed[N*128] node_output[M*3] ypred[N] y_nodepred[M]
    float* o_embed   = (float*)d_out;
    float* o_nodeout = o_embed + (size_t)N * 128;
    float* o_ypred   = o_nodeout + (size_t)M * 3;
    float* o_ynode   = o_ypred + N;

    const int nb = (N + 255) / 256;
    const int ng = (N + 127) / 128;   // GEMM grid

    // ---- CSR build (once; reused by all 3 layers) ----
    hipMemsetAsync(cnt_s, 0, (size_t)2 * N * sizeof(int), stream);
    count_deg<<<(EN + 255) / 256, 256, 0, stream>>>(ei, E, N, cnt_s, cnt_d);
    scan_part<<<nb, 256, 0, stream>>>(cnt_s, bsum_s, N);
    scan_part<<<nb, 256, 0, stream>>>(cnt_d, bsum_d, N);
    scan_bsums<<<1, 1024, 0, stream>>>(bsum_s, nb);
    scan_bsums<<<1, 1024, 0, stream>>>(bsum_d, nb);
    scan_final<<<nb, 256, 0, stream>>>(cnt_s, bsum_s, row_s, N);
    scan_final<<<nb, 256, 0, stream>>>(cnt_d, bsum_d, row_d, N);
    // radix partition into bucket-contiguous staging (CU-local chunk writes)
    init_tails<<<(NB + 255) / 256, 256, 0, stream>>>(row_s, row_d, tail_s, tail_d, NB);
    radix_scatter<<<(EN + SCAT_CHUNK - 1) / SCAT_CHUNK, 256, 0, stream>>>(
        ei, E, N, NB, tail_s, tail_d, bufA_s, bufA_d);
    // place into final CSR rows (one WG per bucket per direction)
    bucket_place<<<dim3(NB, 2), 256, 0, stream>>>(row_s, ent_s, bufA_s,
                                                  row_d, ent_d, bufA_d, N, NB, EN);
    // canonicalize row order -> deterministic float accumulation on every call
    sort_rows_wave<<<(N + 3) / 4, 256, 0, stream>>>(row_s, ent_s, N, EN);
    sort_rows_wave<<<(N + 3) / 4, 256, 0, stream>>>(row_d, ent_d, N, EN);

    // ---- pheno transform: P = x @ phW + phb ----
    gemm_tile<256><<<ng, 256, 0, stream>>>(x, phW, phb, P, N);

    // ---- 3 GAT layers ----
    for (int l = 0; l < 3; ++l) {
        float* tgt = (l == 2) ? o_embed : P;   // layer 3 writes x_embed directly
        gemm_tile<128><<<ng, 256, 0, stream>>>(P, Wl[l], bl[l], Q, N);
        node_dots<<<(N + 3) / 4, 256, 0, stream>>>(Q, attl[l], ai, aj, N);
        softmax_src<<<(N + 3) / 4, 256, 0, stream>>>(row_s, ent_s, ai, aj, amaxF, rden, N, EN);
        aggregate_dst<<<(N + 3) / 4, 256, 0, stream>>>(row_d, ent_d, ai, aj, amaxF, rden,
                                                       Q, bsl[l], tgt, N, EN);
    }

    out_kernel<<<(N + 255) / 256, 256, 0, stream>>>(o_embed, outW, out3, o_ypred, N);
    gather_kernel<<<(M + 255) / 256, 256, 0, stream>>>(nodeix, out3, o_ypred, o_nodeout, o_ynode, M);
}

// Round 10
// 1289.295 us; speedup vs baseline: 1.6735x; 1.0715x over previous
//
#include <hip/hip_runtime.h>
#include <math.h>

// GIG_GAT: pheno GEMM + 3x GATConv with CSR-gather aggregation (no feature atomics),
// CSR-gather segment softmax (no atomics), fused bias+relu epilogue. All fp32.
// CSR build: count/scan -> LDS-binned radix partition -> per-bucket place ->
// wave-bitonic row sort (canonical order -> deterministic float accumulation).
// aggregate_dst: 4-way unrolled edge loop (batched loads, in-order accumulation)
// to break the dependent-load chain (latency-bound at 3.3 of 6.3 TB/s).

#define LRELU_ATT(v) ((v) >= 0.f ? (v) : 0.2f * (v))
#define SCAT_CHUNK 8192

// ---------------- GEMM: Y[N,128] = X[N,K] @ W[K,128] + b ----------------
template <int K>
__global__ __launch_bounds__(256)
void gemm_tile(const float* __restrict__ X, const float* __restrict__ W,
               const float* __restrict__ bvec, float* __restrict__ Y, int N)
{
    __shared__ __align__(16) float xt[32][132];   // [k][row], padded stride
    __shared__ __align__(16) float ws[32][132];   // [k][col], padded stride

    const int t  = threadIdx.x;
    const int tx = t & 15, ty = t >> 4;
    const int r0 = blockIdx.x * 128;

    float acc[8][8];
#pragma unroll
    for (int i = 0; i < 8; ++i)
#pragma unroll
        for (int j = 0; j < 8; ++j) acc[i][j] = 0.f;

    const int srow = t >> 3;          // X stage: 32 rows per pass
    const int sk4  = (t & 7) * 4;
    const int wkr  = t >> 5;          // W stage: 8 k-rows per pass
    const int wc4  = (t & 31) * 4;

    for (int kc = 0; kc < K; kc += 32) {
#pragma unroll
        for (int p = 0; p < 4; ++p) {
            const int r  = srow + p * 32;
            const int gr = r0 + r;
            float4 v = make_float4(0.f, 0.f, 0.f, 0.f);
            if (gr < N) v = *reinterpret_cast<const float4*>(&X[(size_t)gr * K + kc + sk4]);
            xt[sk4 + 0][r] = v.x; xt[sk4 + 1][r] = v.y;
            xt[sk4 + 2][r] = v.z; xt[sk4 + 3][r] = v.w;
        }
#pragma unroll
        for (int p = 0; p < 4; ++p) {
            const int k = wkr + p * 8;
            float4 v = *reinterpret_cast<const float4*>(&W[(size_t)(kc + k) * 128 + wc4]);
            *reinterpret_cast<float4*>(&ws[k][wc4]) = v;
        }
        __syncthreads();

#pragma unroll
        for (int k = 0; k < 32; ++k) {
            const float4 a0 = *reinterpret_cast<const float4*>(&xt[k][8 * ty]);
            const float4 a1 = *reinterpret_cast<const float4*>(&xt[k][8 * ty + 4]);
            const float4 b0 = *reinterpret_cast<const float4*>(&ws[k][8 * tx]);
            const float4 b1 = *reinterpret_cast<const float4*>(&ws[k][8 * tx + 4]);
            const float av[8] = {a0.x, a0.y, a0.z, a0.w, a1.x, a1.y, a1.z, a1.w};
            const float bv[8] = {b0.x, b0.y, b0.z, b0.w, b1.x, b1.y, b1.z, b1.w};
#pragma unroll
            for (int i = 0; i < 8; ++i)
#pragma unroll
                for (int j = 0; j < 8; ++j)
                    acc[i][j] = fmaf(av[i], bv[j], acc[i][j]);
        }
        __syncthreads();
    }

    const float4 bb0 = *reinterpret_cast<const float4*>(&bvec[8 * tx]);
    const float4 bb1 = *reinterpret_cast<const float4*>(&bvec[8 * tx + 4]);
#pragma unroll
    for (int i = 0; i < 8; ++i) {
        const int gr = r0 + 8 * ty + i;
        if (gr < N) {
            float4 o0 = make_float4(acc[i][0] + bb0.x, acc[i][1] + bb0.y,
                                    acc[i][2] + bb0.z, acc[i][3] + bb0.w);
            float4 o1 = make_float4(acc[i][4] + bb1.x, acc[i][5] + bb1.y,
                                    acc[i][6] + bb1.z, acc[i][7] + bb1.w);
            *reinterpret_cast<float4*>(&Y[(size_t)gr * 128 + 8 * tx])     = o0;
            *reinterpret_cast<float4*>(&Y[(size_t)gr * 128 + 8 * tx + 4]) = o1;
        }
    }
}

// ---------------- per-node attention dot products ----------------
__global__ __launch_bounds__(256)
void node_dots(const float* __restrict__ H, const float* __restrict__ att,
               float* __restrict__ ai, float* __restrict__ aj, int N)
{
    const int lane = threadIdx.x & 63;
    const int n    = blockIdx.x * 4 + (threadIdx.x >> 6);
    if (n >= N) return;

    const float v0 = H[(size_t)n * 128 + lane];
    const float v1 = H[(size_t)n * 128 + 64 + lane];
    const int hh = lane >> 5, k = lane & 31;

    float si0 = v0 * att[hh * 64 + k];
    float sj0 = v0 * att[hh * 64 + 32 + k];
    float si1 = v1 * att[(2 + hh) * 64 + k];
    float sj1 = v1 * att[(2 + hh) * 64 + 32 + k];

#pragma unroll
    for (int m = 1; m < 32; m <<= 1) {
        si0 += __shfl_xor(si0, m);
        sj0 += __shfl_xor(sj0, m);
        si1 += __shfl_xor(si1, m);
        sj1 += __shfl_xor(sj1, m);
    }
    if ((lane & 31) == 0) {
        const int hA = lane >> 5;
        ai[(size_t)n * 4 + hA]     = si0;
        aj[(size_t)n * 4 + hA]     = sj0;
        ai[(size_t)n * 4 + 2 + hA] = si1;
        aj[(size_t)n * 4 + 2 + hA] = sj1;
    }
}

// ---------------- CSR build ----------------
__global__ __launch_bounds__(256)
void count_deg(const int* __restrict__ ei, int E, int N,
               int* __restrict__ cnt_s, int* __restrict__ cnt_d)
{
    const int e = blockIdx.x * 256 + threadIdx.x;
    if (e >= E + N) return;
    int s, d;
    if (e < E) { s = ei[e]; d = ei[E + e]; } else { s = d = e - E; }
    atomicAdd(&cnt_s[s], 1);
    atomicAdd(&cnt_d[d], 1);
}

__global__ __launch_bounds__(256)
void scan_part(const int* __restrict__ cnt, int* __restrict__ bsum, int n)
{
    __shared__ int sm[256];
    const int i = blockIdx.x * 256 + threadIdx.x;
    sm[threadIdx.x] = (i < n) ? cnt[i] : 0;
    __syncthreads();
    for (int s = 128; s > 0; s >>= 1) {
        if (threadIdx.x < s) sm[threadIdx.x] += sm[threadIdx.x + s];
        __syncthreads();
    }
    if (threadIdx.x == 0) bsum[blockIdx.x] = sm[0];
}

__global__ __launch_bounds__(1024)
void scan_bsums(int* __restrict__ bsum, int nb)
{
    __shared__ int sm[1024];
    const int i = threadIdx.x;
    if (i < nb) sm[i] = bsum[i];
    __syncthreads();
    if (i == 0) {
        int run = 0;
        for (int t = 0; t < nb; ++t) { int v = sm[t]; sm[t] = run; run += v; }
    }
    __syncthreads();
    if (i < nb) bsum[i] = sm[i];
}

__global__ __launch_bounds__(256)
void scan_final(const int* __restrict__ cnt, const int* __restrict__ bsum,
                int* __restrict__ row, int n)
{
    const int i = blockIdx.x * 256 + threadIdx.x;
    const int lane = threadIdx.x & 63, wid = threadIdx.x >> 6;
    int v = (i < n) ? cnt[i] : 0;
    int inc = v;
#pragma unroll
    for (int d = 1; d < 64; d <<= 1) {
        int y = __shfl_up(inc, d);
        if (lane >= d) inc += y;
    }
    __shared__ int wsum[4];
    if (lane == 63) wsum[wid] = inc;
    __syncthreads();
    int wofs = 0;
    for (int w = 0; w < wid; ++w) wofs += wsum[w];
    if (i < n) row[i] = inc - v + wofs + bsum[blockIdx.x];
}

__global__ __launch_bounds__(256)
void init_tails(const int* __restrict__ row_s, const int* __restrict__ row_d,
                int* __restrict__ tail_s, int* __restrict__ tail_d, int NB)
{
    const int b = blockIdx.x * 256 + threadIdx.x;
    if (b >= NB) return;
    tail_s[b] = row_s[b << 8];
    tail_d[b] = row_d[b << 8];
}

// LDS-binned radix partition: per-WG chunk reservation -> CU-local contiguous writes.
__global__ __launch_bounds__(256)
void radix_scatter(const int* __restrict__ ei, int E, int N, int NB,
                   int* __restrict__ tail_s, int* __restrict__ tail_d,
                   int* __restrict__ bufs, int* __restrict__ bufd)
{
    __shared__ int cnt_s[512], cnt_d[512];
    const int base_e = blockIdx.x * SCAT_CHUNK;
    const int end_e  = min(base_e + SCAT_CHUNK, E + N);

    for (int i = threadIdx.x; i < NB; i += 256) { cnt_s[i] = 0; cnt_d[i] = 0; }
    __syncthreads();

    for (int e = base_e + threadIdx.x; e < end_e; e += 256) {
        int s, d;
        if (e < E) { s = ei[e]; d = ei[E + e]; } else { s = d = e - E; }
        atomicAdd(&cnt_s[s >> 8], 1);
        atomicAdd(&cnt_d[d >> 8], 1);
    }
    __syncthreads();

    for (int b = threadIdx.x; b < NB; b += 256) {
        const int c0 = cnt_s[b];
        cnt_s[b] = c0 ? atomicAdd(&tail_s[b], c0) : 0;
        const int c1 = cnt_d[b];
        cnt_d[b] = c1 ? atomicAdd(&tail_d[b], c1) : 0;
    }
    __syncthreads();

    for (int e = base_e + threadIdx.x; e < end_e; e += 256) {
        int s, d;
        if (e < E) { s = ei[e]; d = ei[E + e]; } else { s = d = e - E; }
        const int ps = atomicAdd(&cnt_s[s >> 8], 1);
        bufs[ps] = ((s & 255) << 17) | d;
        const int pd = atomicAdd(&cnt_d[d >> 8], 1);
        bufd[pd] = ((d & 255) << 17) | s;
    }
}

// One WG per bucket (grid.y = direction): place staged words into final CSR rows.
__global__ __launch_bounds__(256)
void bucket_place(const int* __restrict__ row_s, int* __restrict__ ent_s, const int* __restrict__ bufs,
                  const int* __restrict__ row_d, int* __restrict__ ent_d, const int* __restrict__ bufd,
                  int N, int NB, int EN)
{
    const int* __restrict__ row = (blockIdx.y == 0) ? row_s : row_d;
    int*       __restrict__ ent = (blockIdx.y == 0) ? ent_s : ent_d;
    const int* __restrict__ buf = (blockIdx.y == 0) ? bufs  : bufd;

    __shared__ int fc[256];
    const int node0 = blockIdx.x << 8;
    const int start = row[node0];
    const int nxt   = node0 + 256;
    const int end   = (nxt >= N) ? EN : row[nxt];

    fc[threadIdx.x] = 0;
    __syncthreads();

    for (int i = start + threadIdx.x; i < end; i += 256) {
        const unsigned w  = (unsigned)buf[i];
        const int loc  = (int)(w >> 17);
        const int slot = atomicAdd(&fc[loc], 1);
        ent[row[node0 | loc] + slot] = (int)(w & 0x1FFFFu);
    }
}

// Canonicalize each row ascending (wave bitonic, deg<=64; serial fallback).
__global__ __launch_bounds__(256)
void sort_rows_wave(const int* __restrict__ row, int* __restrict__ ent, int N, int EN)
{
    const int lane = threadIdx.x & 63;
    const int n    = blockIdx.x * 4 + (threadIdx.x >> 6);
    if (n >= N) return;
    const int lo  = row[n];
    const int hi  = (n == N - 1) ? EN : row[n + 1];
    const int deg = hi - lo;

    if (deg > 64) {
        if (lane == 0) {
            for (int i = lo + 1; i < hi; ++i) {
                int v = ent[i], j = i - 1;
                while (j >= lo && ent[j] > v) { ent[j + 1] = ent[j]; --j; }
                ent[j + 1] = v;
            }
        }
        return;
    }

    int v = (lane < deg) ? ent[lo + lane] : 0x7FFFFFFF;
#pragma unroll
    for (int k = 2; k <= 64; k <<= 1) {
#pragma unroll
        for (int j = k >> 1; j > 0; j >>= 1) {
            const int w  = __shfl_xor(v, j);
            const bool up   = ((lane & k) == 0);
            const bool lowr = ((lane & j) == 0);
            v = (lowr == up) ? min(v, w) : max(v, w);
        }
    }
    if (lane < deg) ent[lo + lane] = v;
}

// ---------------- segment softmax grouped by src (gather, no atomics) ----------------
__global__ __launch_bounds__(256)
void softmax_src(const int* __restrict__ row_s, const int* __restrict__ ent_s,
                 const float* __restrict__ ai, const float* __restrict__ aj,
                 float* __restrict__ amaxF, float* __restrict__ rden,
                 int N, int EN)
{
    const int lane = threadIdx.x & 63;
    const int n    = blockIdx.x * 4 + (threadIdx.x >> 6);
    if (n >= N) return;
    const int row = row_s[n];
    const int end = (n == N - 1) ? EN : row_s[n + 1];
    const int slot = lane & 15, h = lane >> 4;
    const float ajh = aj[(size_t)n * 4 + h];

    float m = -INFINITY;
    for (int t = row + slot; t < end; t += 16) {
        const int d = ent_s[t];
        const float a = LRELU_ATT(ai[(size_t)d * 4 + h] + ajh);
        m = fmaxf(m, a);
    }
#pragma unroll
    for (int mm = 1; mm < 16; mm <<= 1) m = fmaxf(m, __shfl_xor(m, mm));

    float ssum = 0.f;
    for (int t = row + slot; t < end; t += 16) {
        const int d = ent_s[t];
        const float a = LRELU_ATT(ai[(size_t)d * 4 + h] + ajh);
        ssum += __expf(a - m);
    }
#pragma unroll
    for (int mm = 1; mm < 16; mm <<= 1) ssum += __shfl_xor(ssum, mm);

    if (slot == 0) {
        amaxF[(size_t)n * 4 + h] = m;
        rden[(size_t)n * 4 + h]  = 1.f / (ssum + 1e-16f);
    }
}

// ---------------- aggregation by dst (gather, no atomics), fused bias+relu ----------
// 4-way unrolled edge loop: batch the ent/H/scalar loads (4 H-rows in flight per
// wave) but accumulate STRICTLY in t order -> identical fmaf order every call.
__global__ __launch_bounds__(256)
void aggregate_dst(const int* __restrict__ row_d, const int* __restrict__ ent_d,
                   const float* __restrict__ ai, const float* __restrict__ aj,
                   const float* __restrict__ amaxF, const float* __restrict__ rden,
                   const float* __restrict__ H, const float* __restrict__ bias,
                   float* __restrict__ OUT, int N, int EN)
{
    const int lane = threadIdx.x & 63;
    const int n    = blockIdx.x * 4 + (threadIdx.x >> 6);
    if (n >= N) return;
    const int row = row_d[n];
    const int end = (n == N - 1) ? EN : row_d[n + 1];
    const int h   = lane >> 4;
    const float aih = ai[(size_t)n * 4 + h];

    float accx = 0.f, accy = 0.f;
    int t = row;
    for (; t + 4 <= end; t += 4) {
        const int s0 = ent_d[t + 0];
        const int s1 = ent_d[t + 1];
        const int s2 = ent_d[t + 2];
        const int s3 = ent_d[t + 3];

        const float2 h0 = *reinterpret_cast<const float2*>(&H[(size_t)s0 * 128 + lane * 2]);
        const float2 h1 = *reinterpret_cast<const float2*>(&H[(size_t)s1 * 128 + lane * 2]);
        const float2 h2 = *reinterpret_cast<const float2*>(&H[(size_t)s2 * 128 + lane * 2]);
        const float2 h3 = *reinterpret_cast<const float2*>(&H[(size_t)s3 * 128 + lane * 2]);

        const float aj0 = aj[(size_t)s0 * 4 + h], m0 = amaxF[(size_t)s0 * 4 + h], r0 = rden[(size_t)s0 * 4 + h];
        const float aj1 = aj[(size_t)s1 * 4 + h], m1 = amaxF[(size_t)s1 * 4 + h], r1 = rden[(size_t)s1 * 4 + h];
        const float aj2 = aj[(size_t)s2 * 4 + h], m2 = amaxF[(size_t)s2 * 4 + h], r2 = rden[(size_t)s2 * 4 + h];
        const float aj3 = aj[(size_t)s3 * 4 + h], m3 = amaxF[(size_t)s3 * 4 + h], r3 = rden[(size_t)s3 * 4 + h];

        float a0 = LRELU_ATT(aih + aj0); const float c0 = __expf(a0 - m0) * r0;
        float a1 = LRELU_ATT(aih + aj1); const float c1 = __expf(a1 - m1) * r1;
        float a2 = LRELU_ATT(aih + aj2); const float c2 = __expf(a2 - m2) * r2;
        float a3 = LRELU_ATT(aih + aj3); const float c3 = __expf(a3 - m3) * r3;

        accx = fmaf(h0.x, c0, accx); accy = fmaf(h0.y, c0, accy);
        accx = fmaf(h1.x, c1, accx); accy = fmaf(h1.y, c1, accy);
        accx = fmaf(h2.x, c2, accx); accy = fmaf(h2.y, c2, accy);
        accx = fmaf(h3.x, c3, accx); accy = fmaf(h3.y, c3, accy);
    }
    for (; t < end; ++t) {
        const int s = ent_d[t];
        const float a    = LRELU_ATT(aih + aj[(size_t)s * 4 + h]);
        const float coef = __expf(a - amaxF[(size_t)s * 4 + h]) * rden[(size_t)s * 4 + h];
        const float2 hv  = *reinterpret_cast<const float2*>(&H[(size_t)s * 128 + lane * 2]);
        accx = fmaf(hv.x, coef, accx);
        accy = fmaf(hv.y, coef, accy);
    }
    const float2 bv = *reinterpret_cast<const float2*>(&bias[lane * 2]);
    OUT[(size_t)n * 128 + lane * 2]     = fmaxf(accx + bv.x, 0.f);
    OUT[(size_t)n * 128 + lane * 2 + 1] = fmaxf(accy + bv.y, 0.f);
}

// ---------------- output head ----------------
__global__ __launch_bounds__(256)
void out_kernel(const float* __restrict__ G, const float* __restrict__ oW,
                float* __restrict__ out3, float* __restrict__ ypredF, int N)
{
    __shared__ float w[384];
    for (int i = threadIdx.x; i < 384; i += 256) w[i] = oW[i];
    __syncthreads();
    const int n = blockIdx.x * 256 + threadIdx.x;
    if (n >= N) return;
    const float* g = G + (size_t)n * 128;
    float a0 = 0.f, a1 = 0.f, a2 = 0.f;
    for (int k = 0; k < 128; k += 4) {
        float4 gv = *reinterpret_cast<const float4*>(&g[k]);
        a0 = fmaf(gv.x, w[(k+0)*3+0], a0); a1 = fmaf(gv.x, w[(k+0)*3+1], a1); a2 = fmaf(gv.x, w[(k+0)*3+2], a2);
        a0 = fmaf(gv.y, w[(k+1)*3+0], a0); a1 = fmaf(gv.y, w[(k+1)*3+1], a1); a2 = fmaf(gv.y, w[(k+1)*3+2], a2);
        a0 = fmaf(gv.z, w[(k+2)*3+0], a0); a1 = fmaf(gv.z, w[(k+2)*3+1], a1); a2 = fmaf(gv.z, w[(k+2)*3+2], a2);
        a0 = fmaf(gv.w, w[(k+3)*3+0], a0); a1 = fmaf(gv.w, w[(k+3)*3+1], a1); a2 = fmaf(gv.w, w[(k+3)*3+2], a2);
    }
    out3[(size_t)n * 3 + 0] = a0;
    out3[(size_t)n * 3 + 1] = a1;
    out3[(size_t)n * 3 + 2] = a2;
    int idx = 0; float best = a0;
    if (a1 > best) { best = a1; idx = 1; }
    if (a2 > best) { best = a2; idx = 2; }
    ypredF[n] = (float)idx;
}

__global__ __launch_bounds__(256)
void gather_kernel(const int* __restrict__ nix, const float* __restrict__ out3,
                   const float* __restrict__ ypredF, float* __restrict__ nodeOut,
                   float* __restrict__ ynode, int M)
{
    const int i = blockIdx.x * 256 + threadIdx.x;
    if (i >= M) return;
    const int n = nix[i];
    nodeOut[(size_t)i * 3 + 0] = out3[(size_t)n * 3 + 0];
    nodeOut[(size_t)i * 3 + 1] = out3[(size_t)n * 3 + 1];
    nodeOut[(size_t)i * 3 + 2] = out3[(size_t)n * 3 + 2];
    ynode[i] = ypredF[n];
}

extern "C" void kernel_launch(void* const* d_in, const int* in_sizes, int n_in,
                              void* d_out, int out_size, void* d_ws, size_t ws_size,
                              hipStream_t stream)
{
    const float* x      = (const float*)d_in[0];
    const int*   ei     = (const int*)d_in[1];
    const int*   nodeix = (const int*)d_in[2];
    const float* phW    = (const float*)d_in[3];
    const float* phb    = (const float*)d_in[4];
    const float* Wl[3]   = {(const float*)d_in[5],  (const float*)d_in[9],  (const float*)d_in[13]};
    const float* bl[3]   = {(const float*)d_in[6],  (const float*)d_in[10], (const float*)d_in[14]};
    const float* attl[3] = {(const float*)d_in[7],  (const float*)d_in[11], (const float*)d_in[15]};
    const float* bsl[3]  = {(const float*)d_in[8],  (const float*)d_in[12], (const float*)d_in[16]};
    const float* outW    = (const float*)d_in[17];

    const int N  = in_sizes[0] / 256;
    const int E  = in_sizes[1] / 2;
    const int M  = in_sizes[2];
    const int EN = E + N;
    const int NB = (N + 255) >> 8;    // 256-node buckets (<=512 for N<=131072)

    // ---- workspace layout ----
    float* P     = (float*)d_ws;                    // N*128
    float* Q     = P + (size_t)N * 128;             // N*128 (aliased as CSR staging below)
    float* ai    = Q + (size_t)N * 128;             // N*4
    float* aj    = ai + (size_t)N * 4;              // N*4
    float* amaxF = aj + (size_t)N * 4;              // N*4
    float* rden  = amaxF + (size_t)N * 4;           // N*4
    float* out3  = rden + (size_t)N * 4;            // N*3
    int* row_s   = (int*)(out3 + (size_t)N * 3);    // N
    int* row_d   = row_s + N;                       // N
    int* cnt_s   = row_d + N;                       // N (degree histogram)
    int* cnt_d   = cnt_s + N;                       // N
    int* tail_s  = cnt_d + N;                       // NB (bucket tails)
    int* tail_d  = tail_s + NB;                     // NB
    int* bsum_s  = tail_d + NB;                     // 1024
    int* bsum_d  = bsum_s + 1024;                   // 1024
    int* ent_s   = bsum_d + 1024;                   // EN
    int* ent_d   = ent_s + (size_t)EN;              // EN

    // staging buffers alias Q (unused until the first GEMM): 2*EN ints <= N*128 floats
    int* bufA_s = (int*)Q;
    int* bufA_d = bufA_s + (size_t)EN;

    // ---- d_out layout: x_embed[N*128] node_output[M*3] ypred[N] y_nodepred[M]
    float* o_embed   = (float*)d_out;
    float* o_nodeout = o_embed + (size_t)N * 128;
    float* o_ypred   = o_nodeout + (size_t)M * 3;
    float* o_ynode   = o_ypred + N;

    const int nb = (N + 255) / 256;
    const int ng = (N + 127) / 128;   // GEMM grid

    // ---- CSR build (once; reused by all 3 layers) ----
    hipMemsetAsync(cnt_s, 0, (size_t)2 * N * sizeof(int), stream);
    count_deg<<<(EN + 255) / 256, 256, 0, stream>>>(ei, E, N, cnt_s, cnt_d);
    scan_part<<<nb, 256, 0, stream>>>(cnt_s, bsum_s, N);
    scan_part<<<nb, 256, 0, stream>>>(cnt_d, bsum_d, N);
    scan_bsums<<<1, 1024, 0, stream>>>(bsum_s, nb);
    scan_bsums<<<1, 1024, 0, stream>>>(bsum_d, nb);
    scan_final<<<nb, 256, 0, stream>>>(cnt_s, bsum_s, row_s, N);
    scan_final<<<nb, 256, 0, stream>>>(cnt_d, bsum_d, row_d, N);
    init_tails<<<(NB + 255) / 256, 256, 0, stream>>>(row_s, row_d, tail_s, tail_d, NB);
    radix_scatter<<<(EN + SCAT_CHUNK - 1) / SCAT_CHUNK, 256, 0, stream>>>(
        ei, E, N, NB, tail_s, tail_d, bufA_s, bufA_d);
    bucket_place<<<dim3(NB, 2), 256, 0, stream>>>(row_s, ent_s, bufA_s,
                                                  row_d, ent_d, bufA_d, N, NB, EN);
    sort_rows_wave<<<(N + 3) / 4, 256, 0, stream>>>(row_s, ent_s, N, EN);
    sort_rows_wave<<<(N + 3) / 4, 256, 0, stream>>>(row_d, ent_d, N, EN);

    // ---- pheno transform: P = x @ phW + phb ----
    gemm_tile<256><<<ng, 256, 0, stream>>>(x, phW, phb, P, N);

    // ---- 3 GAT layers ----
    for (int l = 0; l < 3; ++l) {
        float* tgt = (l == 2) ? o_embed : P;   // layer 3 writes x_embed directly
        gemm_tile<128><<<ng, 256, 0, stream>>>(P, Wl[l], bl[l], Q, N);
        node_dots<<<(N + 3) / 4, 256, 0, stream>>>(Q, attl[l], ai, aj, N);
        softmax_src<<<(N + 3) / 4, 256, 0, stream>>>(row_s, ent_s, ai, aj, amaxF, rden, N, EN);
        aggregate_dst<<<(N + 3) / 4, 256, 0, stream>>>(row_d, ent_d, ai, aj, amaxF, rden,
                                                       Q, bsl[l], tgt, N, EN);
    }

    out_kernel<<<(N + 255) / 256, 256, 0, stream>>>(o_embed, outW, out3, o_ypred, N);
    gather_kernel<<<(M + 255) / 256, 256, 0, stream>>>(nodeix, out3, o_ypred, o_nodeout, o_ynode, M);
}

// Round 12
// 1165.949 us; speedup vs baseline: 1.8505x; 1.1058x over previous
//
#include <hip/hip_runtime.h>
#include <math.h>

// GIG_GAT: pheno GEMM + 3x GATConv with CSR-gather aggregation (no feature atomics),
// CSR-gather segment softmax (no atomics), fused bias+relu epilogue. All fp32.
// CSR build: count/scan -> LDS-binned radix partition -> per-bucket place ->
// wave-bitonic row sort (canonical order -> deterministic float accumulation).
// aggregate_dst: 2 dst-nodes/wave (float4/lane) x 4-way unroll = 8 H-rows in
// flight per wave; per-(node,head) softmax scalars packed in one float4 (pk).
// NOTE(r11 bug): softmax alpha is ai[neighbor] + aj[self] — ai gather restored.

#define LRELU_ATT(v) ((v) >= 0.f ? (v) : 0.2f * (v))
#define SCAT_CHUNK 8192

// ---------------- GEMM: Y[N,128] = X[N,K] @ W[K,128] + b ----------------
template <int K>
__global__ __launch_bounds__(256)
void gemm_tile(const float* __restrict__ X, const float* __restrict__ W,
               const float* __restrict__ bvec, float* __restrict__ Y, int N)
{
    __shared__ __align__(16) float xt[32][132];   // [k][row], padded stride
    __shared__ __align__(16) float ws[32][132];   // [k][col], padded stride

    const int t  = threadIdx.x;
    const int tx = t & 15, ty = t >> 4;
    const int r0 = blockIdx.x * 128;

    float acc[8][8];
#pragma unroll
    for (int i = 0; i < 8; ++i)
#pragma unroll
        for (int j = 0; j < 8; ++j) acc[i][j] = 0.f;

    const int srow = t >> 3;          // X stage: 32 rows per pass
    const int sk4  = (t & 7) * 4;
    const int wkr  = t >> 5;          // W stage: 8 k-rows per pass
    const int wc4  = (t & 31) * 4;

    for (int kc = 0; kc < K; kc += 32) {
#pragma unroll
        for (int p = 0; p < 4; ++p) {
            const int r  = srow + p * 32;
            const int gr = r0 + r;
            float4 v = make_float4(0.f, 0.f, 0.f, 0.f);
            if (gr < N) v = *reinterpret_cast<const float4*>(&X[(size_t)gr * K + kc + sk4]);
            xt[sk4 + 0][r] = v.x; xt[sk4 + 1][r] = v.y;
            xt[sk4 + 2][r] = v.z; xt[sk4 + 3][r] = v.w;
        }
#pragma unroll
        for (int p = 0; p < 4; ++p) {
            const int k = wkr + p * 8;
            float4 v = *reinterpret_cast<const float4*>(&W[(size_t)(kc + k) * 128 + wc4]);
            *reinterpret_cast<float4*>(&ws[k][wc4]) = v;
        }
        __syncthreads();

#pragma unroll
        for (int k = 0; k < 32; ++k) {
            const float4 a0 = *reinterpret_cast<const float4*>(&xt[k][8 * ty]);
            const float4 a1 = *reinterpret_cast<const float4*>(&xt[k][8 * ty + 4]);
            const float4 b0 = *reinterpret_cast<const float4*>(&ws[k][8 * tx]);
            const float4 b1 = *reinterpret_cast<const float4*>(&ws[k][8 * tx + 4]);
            const float av[8] = {a0.x, a0.y, a0.z, a0.w, a1.x, a1.y, a1.z, a1.w};
            const float bv[8] = {b0.x, b0.y, b0.z, b0.w, b1.x, b1.y, b1.z, b1.w};
#pragma unroll
            for (int i = 0; i < 8; ++i)
#pragma unroll
                for (int j = 0; j < 8; ++j)
                    acc[i][j] = fmaf(av[i], bv[j], acc[i][j]);
        }
        __syncthreads();
    }

    const float4 bb0 = *reinterpret_cast<const float4*>(&bvec[8 * tx]);
    const float4 bb1 = *reinterpret_cast<const float4*>(&bvec[8 * tx + 4]);
#pragma unroll
    for (int i = 0; i < 8; ++i) {
        const int gr = r0 + 8 * ty + i;
        if (gr < N) {
            float4 o0 = make_float4(acc[i][0] + bb0.x, acc[i][1] + bb0.y,
                                    acc[i][2] + bb0.z, acc[i][3] + bb0.w);
            float4 o1 = make_float4(acc[i][4] + bb1.x, acc[i][5] + bb1.y,
                                    acc[i][6] + bb1.z, acc[i][7] + bb1.w);
            *reinterpret_cast<float4*>(&Y[(size_t)gr * 128 + 8 * tx])     = o0;
            *reinterpret_cast<float4*>(&Y[(size_t)gr * 128 + 8 * tx + 4]) = o1;
        }
    }
}

// ---------------- per-node attention dot products ----------------
// ai[n,h] = dot(H[n,h*32..], att[h,0..32)); pk[n*4+h].x = dot(.., att[h,32..64))
__global__ __launch_bounds__(256)
void node_dots(const float* __restrict__ H, const float* __restrict__ att,
               float* __restrict__ ai, float4* __restrict__ pk, int N)
{
    const int lane = threadIdx.x & 63;
    const int n    = blockIdx.x * 4 + (threadIdx.x >> 6);
    if (n >= N) return;

    const float v0 = H[(size_t)n * 128 + lane];
    const float v1 = H[(size_t)n * 128 + 64 + lane];
    const int hh = lane >> 5, k = lane & 31;

    float si0 = v0 * att[hh * 64 + k];
    float sj0 = v0 * att[hh * 64 + 32 + k];
    float si1 = v1 * att[(2 + hh) * 64 + k];
    float sj1 = v1 * att[(2 + hh) * 64 + 32 + k];

#pragma unroll
    for (int m = 1; m < 32; m <<= 1) {
        si0 += __shfl_xor(si0, m);
        sj0 += __shfl_xor(sj0, m);
        si1 += __shfl_xor(si1, m);
        sj1 += __shfl_xor(sj1, m);
    }
    if ((lane & 31) == 0) {
        const int hA = lane >> 5;
        ai[(size_t)n * 4 + hA]     = si0;
        ai[(size_t)n * 4 + 2 + hA] = si1;
        ((float*)&pk[(size_t)n * 4 + hA])[0]     = sj0;
        ((float*)&pk[(size_t)n * 4 + 2 + hA])[0] = sj1;
    }
}

// ---------------- CSR build ----------------
__global__ __launch_bounds__(256)
void count_deg(const int* __restrict__ ei, int E, int N,
               int* __restrict__ cnt_s, int* __restrict__ cnt_d)
{
    const int e = blockIdx.x * 256 + threadIdx.x;
    if (e >= E + N) return;
    int s, d;
    if (e < E) { s = ei[e]; d = ei[E + e]; } else { s = d = e - E; }
    atomicAdd(&cnt_s[s], 1);
    atomicAdd(&cnt_d[d], 1);
}

__global__ __launch_bounds__(256)
void scan_part(const int* __restrict__ cnt, int* __restrict__ bsum, int n)
{
    __shared__ int sm[256];
    const int i = blockIdx.x * 256 + threadIdx.x;
    sm[threadIdx.x] = (i < n) ? cnt[i] : 0;
    __syncthreads();
    for (int s = 128; s > 0; s >>= 1) {
        if (threadIdx.x < s) sm[threadIdx.x] += sm[threadIdx.x + s];
        __syncthreads();
    }
    if (threadIdx.x == 0) bsum[blockIdx.x] = sm[0];
}

__global__ __launch_bounds__(1024)
void scan_bsums(int* __restrict__ bsum, int nb)
{
    __shared__ int sm[1024];
    const int i = threadIdx.x;
    if (i < nb) sm[i] = bsum[i];
    __syncthreads();
    if (i == 0) {
        int run = 0;
        for (int t = 0; t < nb; ++t) { int v = sm[t]; sm[t] = run; run += v; }
    }
    __syncthreads();
    if (i < nb) bsum[i] = sm[i];
}

__global__ __launch_bounds__(256)
void scan_final(const int* __restrict__ cnt, const int* __restrict__ bsum,
                int* __restrict__ row, int n)
{
    const int i = blockIdx.x * 256 + threadIdx.x;
    const int lane = threadIdx.x & 63, wid = threadIdx.x >> 6;
    int v = (i < n) ? cnt[i] : 0;
    int inc = v;
#pragma unroll
    for (int d = 1; d < 64; d <<= 1) {
        int y = __shfl_up(inc, d);
        if (lane >= d) inc += y;
    }
    __shared__ int wsum[4];
    if (lane == 63) wsum[wid] = inc;
    __syncthreads();
    int wofs = 0;
    for (int w = 0; w < wid; ++w) wofs += wsum[w];
    if (i < n) row[i] = inc - v + wofs + bsum[blockIdx.x];
}

__global__ __launch_bounds__(256)
void init_tails(const int* __restrict__ row_s, const int* __restrict__ row_d,
                int* __restrict__ tail_s, int* __restrict__ tail_d, int NB)
{
    const int b = blockIdx.x * 256 + threadIdx.x;
    if (b >= NB) return;
    tail_s[b] = row_s[b << 8];
    tail_d[b] = row_d[b << 8];
}

// LDS-binned radix partition: per-WG chunk reservation -> CU-local contiguous writes.
__global__ __launch_bounds__(256)
void radix_scatter(const int* __restrict__ ei, int E, int N, int NB,
                   int* __restrict__ tail_s, int* __restrict__ tail_d,
                   int* __restrict__ bufs, int* __restrict__ bufd)
{
    __shared__ int cnt_s[512], cnt_d[512];
    const int base_e = blockIdx.x * SCAT_CHUNK;
    const int end_e  = min(base_e + SCAT_CHUNK, E + N);

    for (int i = threadIdx.x; i < NB; i += 256) { cnt_s[i] = 0; cnt_d[i] = 0; }
    __syncthreads();

    for (int e = base_e + threadIdx.x; e < end_e; e += 256) {
        int s, d;
        if (e < E) { s = ei[e]; d = ei[E + e]; } else { s = d = e - E; }
        atomicAdd(&cnt_s[s >> 8], 1);
        atomicAdd(&cnt_d[d >> 8], 1);
    }
    __syncthreads();

    for (int b = threadIdx.x; b < NB; b += 256) {
        const int c0 = cnt_s[b];
        cnt_s[b] = c0 ? atomicAdd(&tail_s[b], c0) : 0;
        const int c1 = cnt_d[b];
        cnt_d[b] = c1 ? atomicAdd(&tail_d[b], c1) : 0;
    }
    __syncthreads();

    for (int e = base_e + threadIdx.x; e < end_e; e += 256) {
        int s, d;
        if (e < E) { s = ei[e]; d = ei[E + e]; } else { s = d = e - E; }
        const int ps = atomicAdd(&cnt_s[s >> 8], 1);
        bufs[ps] = ((s & 255) << 17) | d;
        const int pd = atomicAdd(&cnt_d[d >> 8], 1);
        bufd[pd] = ((d & 255) << 17) | s;
    }
}

// One WG per bucket (grid.y = direction): place staged words into final CSR rows.
__global__ __launch_bounds__(256)
void bucket_place(const int* __restrict__ row_s, int* __restrict__ ent_s, const int* __restrict__ bufs,
                  const int* __restrict__ row_d, int* __restrict__ ent_d, const int* __restrict__ bufd,
                  int N, int NB, int EN)
{
    const int* __restrict__ row = (blockIdx.y == 0) ? row_s : row_d;
    int*       __restrict__ ent = (blockIdx.y == 0) ? ent_s : ent_d;
    const int* __restrict__ buf = (blockIdx.y == 0) ? bufs  : bufd;

    __shared__ int fc[256];
    const int node0 = blockIdx.x << 8;
    const int start = row[node0];
    const int nxt   = node0 + 256;
    const int end   = (nxt >= N) ? EN : row[nxt];

    fc[threadIdx.x] = 0;
    __syncthreads();

    for (int i = start + threadIdx.x; i < end; i += 256) {
        const unsigned w  = (unsigned)buf[i];
        const int loc  = (int)(w >> 17);
        const int slot = atomicAdd(&fc[loc], 1);
        ent[row[node0 | loc] + slot] = (int)(w & 0x1FFFFu);
    }
}

// Canonicalize each row ascending (wave bitonic, deg<=64; serial fallback).
__global__ __launch_bounds__(256)
void sort_rows_wave(const int* __restrict__ row, int* __restrict__ ent, int N, int EN)
{
    const int lane = threadIdx.x & 63;
    const int n    = blockIdx.x * 4 + (threadIdx.x >> 6);
    if (n >= N) return;
    const int lo  = row[n];
    const int hi  = (n == N - 1) ? EN : row[n + 1];
    const int deg = hi - lo;

    if (deg > 64) {
        if (lane == 0) {
            for (int i = lo + 1; i < hi; ++i) {
                int v = ent[i], j = i - 1;
                while (j >= lo && ent[j] > v) { ent[j + 1] = ent[j]; --j; }
                ent[j + 1] = v;
            }
        }
        return;
    }

    int v = (lane < deg) ? ent[lo + lane] : 0x7FFFFFFF;
#pragma unroll
    for (int k = 2; k <= 64; k <<= 1) {
#pragma unroll
        for (int j = k >> 1; j > 0; j >>= 1) {
            const int w  = __shfl_xor(v, j);
            const bool up   = ((lane & k) == 0);
            const bool lowr = ((lane & j) == 0);
            v = (lowr == up) ? min(v, w) : max(v, w);
        }
    }
    if (lane < deg) ent[lo + lane] = v;
}

// ---------------- segment softmax grouped by src (gather, no atomics) ------------
// One wave per src node: lane = slot(0..15) x head(0..3). alpha = ai[d] + aj[n].
// Single gather pass: per-slot alphas cached in registers (deg<=64 -> <=4/slot;
// exp(-inf)=0 pads exactly). Writes pk[n*4+h].y = max, .z = 1/(sum+eps).
__global__ __launch_bounds__(256)
void softmax_src(const int* __restrict__ row_s, const int* __restrict__ ent_s,
                 const float* __restrict__ ai, float4* __restrict__ pk, int N, int EN)
{
    const int lane = threadIdx.x & 63;
    const int n    = blockIdx.x * 4 + (threadIdx.x >> 6);
    if (n >= N) return;
    const int row = row_s[n];
    const int end = (n == N - 1) ? EN : row_s[n + 1];
    const int deg = end - row;
    const int slot = lane & 15, h = lane >> 4;
    const float ajh = ((const float*)&pk[(size_t)n * 4 + h])[0];

    float m, ssum;
    if (deg <= 64) {
        float a0 = -INFINITY, a1 = -INFINITY, a2 = -INFINITY, a3 = -INFINITY;
        int t = row + slot;
        if (t < end) { a0 = LRELU_ATT(ai[(size_t)ent_s[t] * 4 + h] + ajh); t += 16; }
        if (t < end) { a1 = LRELU_ATT(ai[(size_t)ent_s[t] * 4 + h] + ajh); t += 16; }
        if (t < end) { a2 = LRELU_ATT(ai[(size_t)ent_s[t] * 4 + h] + ajh); t += 16; }
        if (t < end) { a3 = LRELU_ATT(ai[(size_t)ent_s[t] * 4 + h] + ajh); }
        m = fmaxf(fmaxf(a0, a1), fmaxf(a2, a3));
#pragma unroll
        for (int mm = 1; mm < 16; mm <<= 1) m = fmaxf(m, __shfl_xor(m, mm));
        ssum = __expf(a0 - m);      // exp(-inf - m) == 0 for padded slots
        ssum += __expf(a1 - m);
        ssum += __expf(a2 - m);
        ssum += __expf(a3 - m);
#pragma unroll
        for (int mm = 1; mm < 16; mm <<= 1) ssum += __shfl_xor(ssum, mm);
    } else {
        m = -INFINITY;
        for (int t = row + slot; t < end; t += 16) {
            const int d = ent_s[t];
            const float a = LRELU_ATT(ai[(size_t)d * 4 + h] + ajh);
            m = fmaxf(m, a);
        }
#pragma unroll
        for (int mm = 1; mm < 16; mm <<= 1) m = fmaxf(m, __shfl_xor(m, mm));
        ssum = 0.f;
        for (int t = row + slot; t < end; t += 16) {
            const int d = ent_s[t];
            const float a = LRELU_ATT(ai[(size_t)d * 4 + h] + ajh);
            ssum += __expf(a - m);
        }
#pragma unroll
        for (int mm = 1; mm < 16; mm <<= 1) ssum += __shfl_xor(ssum, mm);
    }

    if (slot == 0) {
        float* p = (float*)&pk[(size_t)n * 4 + h];
        p[1] = m;
        p[2] = 1.f / (ssum + 1e-16f);
    }
}

// ---------------- aggregation by dst (gather, no atomics), fused bias+relu -------
// 2 dst-nodes per wave (half-wave = 32 lanes x float4 = one 512B H row), 4-way
// unrolled -> 8 H-rows in flight per wave. Strict t-order accumulation per row.
__global__ __launch_bounds__(256)
void aggregate_dst(const int* __restrict__ row_d, const int* __restrict__ ent_d,
                   const float* __restrict__ ai, const float4* __restrict__ pk,
                   const float* __restrict__ H, const float* __restrict__ bias,
                   float* __restrict__ OUT, int N, int EN)
{
    const int lane = threadIdx.x & 63;
    const int half = lane >> 5, ll = lane & 31;
    const int n    = blockIdx.x * 8 + (threadIdx.x >> 6) * 2 + half;
    if (n >= N) return;
    const int row = row_d[n];
    const int end = (n == N - 1) ? EN : row_d[n + 1];
    const int h   = ll >> 3;                    // features [4ll,4ll+4) -> head
    const float aih = ai[(size_t)n * 4 + h];

    float4 acc = make_float4(0.f, 0.f, 0.f, 0.f);
    int t = row;
    for (; t + 4 <= end; t += 4) {
        const int s0 = ent_d[t + 0];
        const int s1 = ent_d[t + 1];
        const int s2 = ent_d[t + 2];
        const int s3 = ent_d[t + 3];

        const float4 h0 = *reinterpret_cast<const float4*>(&H[(size_t)s0 * 128 + ll * 4]);
        const float4 h1 = *reinterpret_cast<const float4*>(&H[(size_t)s1 * 128 + ll * 4]);
        const float4 h2 = *reinterpret_cast<const float4*>(&H[(size_t)s2 * 128 + ll * 4]);
        const float4 h3 = *reinterpret_cast<const float4*>(&H[(size_t)s3 * 128 + ll * 4]);

        const float4 p0 = pk[(size_t)s0 * 4 + h];
        const float4 p1 = pk[(size_t)s1 * 4 + h];
        const float4 p2 = pk[(size_t)s2 * 4 + h];
        const float4 p3 = pk[(size_t)s3 * 4 + h];

        const float c0 = __expf(LRELU_ATT(aih + p0.x) - p0.y) * p0.z;
        const float c1 = __expf(LRELU_ATT(aih + p1.x) - p1.y) * p1.z;
        const float c2 = __expf(LRELU_ATT(aih + p2.x) - p2.y) * p2.z;
        const float c3 = __expf(LRELU_ATT(aih + p3.x) - p3.y) * p3.z;

        acc.x = fmaf(h0.x, c0, acc.x); acc.y = fmaf(h0.y, c0, acc.y);
        acc.z = fmaf(h0.z, c0, acc.z); acc.w = fmaf(h0.w, c0, acc.w);
        acc.x = fmaf(h1.x, c1, acc.x); acc.y = fmaf(h1.y, c1, acc.y);
        acc.z = fmaf(h1.z, c1, acc.z); acc.w = fmaf(h1.w, c1, acc.w);
        acc.x = fmaf(h2.x, c2, acc.x); acc.y = fmaf(h2.y, c2, acc.y);
        acc.z = fmaf(h2.z, c2, acc.z); acc.w = fmaf(h2.w, c2, acc.w);
        acc.x = fmaf(h3.x, c3, acc.x); acc.y = fmaf(h3.y, c3, acc.y);
        acc.z = fmaf(h3.z, c3, acc.z); acc.w = fmaf(h3.w, c3, acc.w);
    }
    for (; t < end; ++t) {
        const int s = ent_d[t];
        const float4 hv = *reinterpret_cast<const float4*>(&H[(size_t)s * 128 + ll * 4]);
        const float4 pv = pk[(size_t)s * 4 + h];
        const float c   = __expf(LRELU_ATT(aih + pv.x) - pv.y) * pv.z;
        acc.x = fmaf(hv.x, c, acc.x); acc.y = fmaf(hv.y, c, acc.y);
        acc.z = fmaf(hv.z, c, acc.z); acc.w = fmaf(hv.w, c, acc.w);
    }
    const float4 bv = *reinterpret_cast<const float4*>(&bias[ll * 4]);
    float4 o;
    o.x = fmaxf(acc.x + bv.x, 0.f);
    o.y = fmaxf(acc.y + bv.y, 0.f);
    o.z = fmaxf(acc.z + bv.z, 0.f);
    o.w = fmaxf(acc.w + bv.w, 0.f);
    *reinterpret_cast<float4*>(&OUT[(size_t)n * 128 + ll * 4]) = o;
}

// ---------------- output head ----------------
__global__ __launch_bounds__(256)
void out_kernel(const float* __restrict__ G, const float* __restrict__ oW,
                float* __restrict__ out3, float* __restrict__ ypredF, int N)
{
    __shared__ float w[384];
    for (int i = threadIdx.x; i < 384; i += 256) w[i] = oW[i];
    __syncthreads();
    const int n = blockIdx.x * 256 + threadIdx.x;
    if (n >= N) return;
    const float* g = G + (size_t)n * 128;
    float a0 = 0.f, a1 = 0.f, a2 = 0.f;
    for (int k = 0; k < 128; k += 4) {
        float4 gv = *reinterpret_cast<const float4*>(&g[k]);
        a0 = fmaf(gv.x, w[(k+0)*3+0], a0); a1 = fmaf(gv.x, w[(k+0)*3+1], a1); a2 = fmaf(gv.x, w[(k+0)*3+2], a2);
        a0 = fmaf(gv.y, w[(k+1)*3+0], a0); a1 = fmaf(gv.y, w[(k+1)*3+1], a1); a2 = fmaf(gv.y, w[(k+1)*3+2], a2);
        a0 = fmaf(gv.z, w[(k+2)*3+0], a0); a1 = fmaf(gv.z, w[(k+2)*3+1], a1); a2 = fmaf(gv.z, w[(k+2)*3+2], a2);
        a0 = fmaf(gv.w, w[(k+3)*3+0], a0); a1 = fmaf(gv.w, w[(k+3)*3+1], a1); a2 = fmaf(gv.w, w[(k+3)*3+2], a2);
    }
    out3[(size_t)n * 3 + 0] = a0;
    out3[(size_t)n * 3 + 1] = a1;
    out3[(size_t)n * 3 + 2] = a2;
    int idx = 0; float best = a0;
    if (a1 > best) { best = a1; idx = 1; }
    if (a2 > best) { best = a2; idx = 2; }
    ypredF[n] = (float)idx;
}

__global__ __launch_bounds__(256)
void gather_kernel(const int* __restrict__ nix, const float* __restrict__ out3,
                   const float* __restrict__ ypredF, float* __restrict__ nodeOut,
                   float* __restrict__ ynode, int M)
{
    const int i = blockIdx.x * 256 + threadIdx.x;
    if (i >= M) return;
    const int n = nix[i];
    nodeOut[(size_t)i * 3 + 0] = out3[(size_t)n * 3 + 0];
    nodeOut[(size_t)i * 3 + 1] = out3[(size_t)n * 3 + 1];
    nodeOut[(size_t)i * 3 + 2] = out3[(size_t)n * 3 + 2];
    ynode[i] = ypredF[n];
}

extern "C" void kernel_launch(void* const* d_in, const int* in_sizes, int n_in,
                              void* d_out, int out_size, void* d_ws, size_t ws_size,
                              hipStream_t stream)
{
    const float* x      = (const float*)d_in[0];
    const int*   ei     = (const int*)d_in[1];
    const int*   nodeix = (const int*)d_in[2];
    const float* phW    = (const float*)d_in[3];
    const float* phb    = (const float*)d_in[4];
    const float* Wl[3]   = {(const float*)d_in[5],  (const float*)d_in[9],  (const float*)d_in[13]};
    const float* bl[3]   = {(const float*)d_in[6],  (const float*)d_in[10], (const float*)d_in[14]};
    const float* attl[3] = {(const float*)d_in[7],  (const float*)d_in[11], (const float*)d_in[15]};
    const float* bsl[3]  = {(const float*)d_in[8],  (const float*)d_in[12], (const float*)d_in[16]};
    const float* outW    = (const float*)d_in[17];

    const int N  = in_sizes[0] / 256;
    const int E  = in_sizes[1] / 2;
    const int M  = in_sizes[2];
    const int EN = E + N;
    const int NB = (N + 255) >> 8;    // 256-node buckets (<=512 for N<=131072)

    // ---- workspace layout ----
    float*  P     = (float*)d_ws;                     // N*128
    float*  Q     = P + (size_t)N * 128;              // N*128 (aliased as CSR staging)
    float*  ai    = Q + (size_t)N * 128;              // N*4
    float4* pk    = (float4*)(ai + (size_t)N * 4);    // N*4 float4 {aj, amax, rden, -}
    float*  out3  = (float*)(pk + (size_t)N * 4);     // N*3
    int* row_s   = (int*)(out3 + (size_t)N * 3);      // N
    int* row_d   = row_s + N;                         // N
    int* cnt_s   = row_d + N;                         // N (degree histogram)
    int* cnt_d   = cnt_s + N;                         // N
    int* tail_s  = cnt_d + N;                         // NB (bucket tails)
    int* tail_d  = tail_s + NB;                       // NB
    int* bsum_s  = tail_d + NB;                       // 1024
    int* bsum_d  = bsum_s + 1024;                     // 1024
    int* ent_s   = bsum_d + 1024;                     // EN
    int* ent_d   = ent_s + (size_t)EN;                // EN

    // staging buffers alias Q (unused until the first GEMM): 2*EN ints <= N*128 floats
    int* bufA_s = (int*)Q;
    int* bufA_d = bufA_s + (size_t)EN;

    // ---- d_out layout: x_embed[N*128] node_output[M*3] ypred[N] y_nodepred[M]
    float* o_embed   = (float*)d_out;
    float* o_nodeout = o_embed + (size_t)N * 128;
    float* o_ypred   = o_nodeout + (size_t)M * 3;
    float* o_ynode   = o_ypred + N;

    const int nb = (N + 255) / 256;
    const int ng = (N + 127) / 128;   // GEMM grid

    // ---- CSR build (once; reused by all 3 layers) ----
    hipMemsetAsync(cnt_s, 0, (size_t)2 * N * sizeof(int), stream);
    count_deg<<<(EN + 255) / 256, 256, 0, stream>>>(ei, E, N, cnt_s, cnt_d);
    scan_part<<<nb, 256, 0, stream>>>(cnt_s, bsum_s, N);
    scan_part<<<nb, 256, 0, stream>>>(cnt_d, bsum_d, N);
    scan_bsums<<<1, 1024, 0, stream>>>(bsum_s, nb);
    scan_bsums<<<1, 1024, 0, stream>>>(bsum_d, nb);
    scan_final<<<nb, 256, 0, stream>>>(cnt_s, bsum_s, row_s, N);
    scan_final<<<nb, 256, 0, stream>>>(cnt_d, bsum_d, row_d, N);
    init_tails<<<(NB + 255) / 256, 256, 0, stream>>>(row_s, row_d, tail_s, tail_d, NB);
    radix_scatter<<<(EN + SCAT_CHUNK - 1) / SCAT_CHUNK, 256, 0, stream>>>(
        ei, E, N, NB, tail_s, tail_d, bufA_s, bufA_d);
    bucket_place<<<dim3(NB, 2), 256, 0, stream>>>(row_s, ent_s, bufA_s,
                                                  row_d, ent_d, bufA_d, N, NB, EN);
    sort_rows_wave<<<(N + 3) / 4, 256, 0, stream>>>(row_s, ent_s, N, EN);
    sort_rows_wave<<<(N + 3) / 4, 256, 0, stream>>>(row_d, ent_d, N, EN);

    // ---- pheno transform: P = x @ phW + phb ----
    gemm_tile<256><<<ng, 256, 0, stream>>>(x, phW, phb, P, N);

    // ---- 3 GAT layers ----
    for (int l = 0; l < 3; ++l) {
        float* tgt = (l == 2) ? o_embed : P;   // layer 3 writes x_embed directly
        gemm_tile<128><<<ng, 256, 0, stream>>>(P, Wl[l], bl[l], Q, N);
        node_dots<<<(N + 3) / 4, 256, 0, stream>>>(Q, attl[l], ai, pk, N);
        softmax_src<<<(N + 3) / 4, 256, 0, stream>>>(row_s, ent_s, ai, pk, N, EN);
        aggregate_dst<<<(N + 7) / 8, 256, 0, stream>>>(row_d, ent_d, ai, pk,
                                                       Q, bsl[l], tgt, N, EN);
    }

    out_kernel<<<(N + 255) / 256, 256, 0, stream>>>(o_embed, outW, out3, o_ypred, N);
    gather_kernel<<<(M + 255) / 256, 256, 0, stream>>>(nodeix, out3, o_ypred, o_nodeout, o_ynode, M);
}

// Round 13
// 1098.808 us; speedup vs baseline: 1.9636x; 1.0611x over previous
//
#include <hip/hip_runtime.h>
#include <math.h>

// GIG_GAT: pheno GEMM + 3x GATConv with CSR-gather aggregation (no feature atomics),
// CSR-gather segment softmax (no atomics), fused bias+relu epilogue. All fp32.
// CSR build: count/scan (paired via grid.y, tails fused) -> LDS-binned radix
// partition -> per-bucket place -> wave-bitonic row sort (canonical order ->
// deterministic float accumulation). Attention dots fused into GEMM epilogue.
// aggregate_dst: 2 dst-nodes/wave (float4/lane) x 4-way unroll, int4 index loads.

#define LRELU_ATT(v) ((v) >= 0.f ? (v) : 0.2f * (v))
#define SCAT_CHUNK 8192

// ---------------- GEMM: Y[N,128] = X[N,K] @ W[K,128] + b (+ fused att dots) ------
// Block: 256 threads = 16(tx) x 16(ty); thread tile 8x8. When DOTS: each thread's
// 8 cols lie in one head (h = tx>>2); per row compute partial dots with att and
// reduce over the 4-thread col group via shfl_xor(1),(2) -> ai[n,h], pk[n,h].x.
template <int K, bool DOTS>
__global__ __launch_bounds__(256)
void gemm_tile(const float* __restrict__ X, const float* __restrict__ W,
               const float* __restrict__ bvec, float* __restrict__ Y,
               const float* __restrict__ att, float* __restrict__ ai,
               float4* __restrict__ pk, int N)
{
    __shared__ __align__(16) float xt[32][132];   // [k][row], padded stride
    __shared__ __align__(16) float ws[32][132];   // [k][col], padded stride

    const int t  = threadIdx.x;
    const int tx = t & 15, ty = t >> 4;
    const int r0 = blockIdx.x * 128;

    float acc[8][8];
#pragma unroll
    for (int i = 0; i < 8; ++i)
#pragma unroll
        for (int j = 0; j < 8; ++j) acc[i][j] = 0.f;

    const int srow = t >> 3;          // X stage: 32 rows per pass
    const int sk4  = (t & 7) * 4;
    const int wkr  = t >> 5;          // W stage: 8 k-rows per pass
    const int wc4  = (t & 31) * 4;

    for (int kc = 0; kc < K; kc += 32) {
#pragma unroll
        for (int p = 0; p < 4; ++p) {
            const int r  = srow + p * 32;
            const int gr = r0 + r;
            float4 v = make_float4(0.f, 0.f, 0.f, 0.f);
            if (gr < N) v = *reinterpret_cast<const float4*>(&X[(size_t)gr * K + kc + sk4]);
            xt[sk4 + 0][r] = v.x; xt[sk4 + 1][r] = v.y;
            xt[sk4 + 2][r] = v.z; xt[sk4 + 3][r] = v.w;
        }
#pragma unroll
        for (int p = 0; p < 4; ++p) {
            const int k = wkr + p * 8;
            float4 v = *reinterpret_cast<const float4*>(&W[(size_t)(kc + k) * 128 + wc4]);
            *reinterpret_cast<float4*>(&ws[k][wc4]) = v;
        }
        __syncthreads();

#pragma unroll
        for (int k = 0; k < 32; ++k) {
            const float4 a0 = *reinterpret_cast<const float4*>(&xt[k][8 * ty]);
            const float4 a1 = *reinterpret_cast<const float4*>(&xt[k][8 * ty + 4]);
            const float4 b0 = *reinterpret_cast<const float4*>(&ws[k][8 * tx]);
            const float4 b1 = *reinterpret_cast<const float4*>(&ws[k][8 * tx + 4]);
            const float av[8] = {a0.x, a0.y, a0.z, a0.w, a1.x, a1.y, a1.z, a1.w};
            const float bv[8] = {b0.x, b0.y, b0.z, b0.w, b1.x, b1.y, b1.z, b1.w};
#pragma unroll
            for (int i = 0; i < 8; ++i)
#pragma unroll
                for (int j = 0; j < 8; ++j)
                    acc[i][j] = fmaf(av[i], bv[j], acc[i][j]);
        }
        __syncthreads();
    }

    const float4 bb0 = *reinterpret_cast<const float4*>(&bvec[8 * tx]);
    const float4 bb1 = *reinterpret_cast<const float4*>(&bvec[8 * tx + 4]);

    // att fragments for this thread's head/column window (only if DOTS)
    const int h  = tx >> 2;
    const int k0 = (8 * tx) & 31;
    float4 ati0, ati1, atj0, atj1;
    if (DOTS) {
        ati0 = *reinterpret_cast<const float4*>(&att[h * 64 + k0]);
        ati1 = *reinterpret_cast<const float4*>(&att[h * 64 + k0 + 4]);
        atj0 = *reinterpret_cast<const float4*>(&att[h * 64 + 32 + k0]);
        atj1 = *reinterpret_cast<const float4*>(&att[h * 64 + 32 + k0 + 4]);
    }

#pragma unroll
    for (int i = 0; i < 8; ++i) {
        const int gr = r0 + 8 * ty + i;
        float4 o0 = make_float4(acc[i][0] + bb0.x, acc[i][1] + bb0.y,
                                acc[i][2] + bb0.z, acc[i][3] + bb0.w);
        float4 o1 = make_float4(acc[i][4] + bb1.x, acc[i][5] + bb1.y,
                                acc[i][6] + bb1.z, acc[i][7] + bb1.w);
        if (gr < N) {
            *reinterpret_cast<float4*>(&Y[(size_t)gr * 128 + 8 * tx])     = o0;
            *reinterpret_cast<float4*>(&Y[(size_t)gr * 128 + 8 * tx + 4]) = o1;
        }
        if (DOTS) {
            float pi = o0.x * ati0.x + o0.y * ati0.y + o0.z * ati0.z + o0.w * ati0.w
                     + o1.x * ati1.x + o1.y * ati1.y + o1.z * ati1.z + o1.w * ati1.w;
            float pj = o0.x * atj0.x + o0.y * atj0.y + o0.z * atj0.z + o0.w * atj0.w
                     + o1.x * atj1.x + o1.y * atj1.y + o1.z * atj1.z + o1.w * atj1.w;
            // reduce over the 4 threads (tx&3) sharing this (row, head)
            pi += __shfl_xor(pi, 1); pi += __shfl_xor(pi, 2);
            pj += __shfl_xor(pj, 1); pj += __shfl_xor(pj, 2);
            if ((tx & 3) == 0 && gr < N) {
                ai[(size_t)gr * 4 + h] = pi;
                ((float*)&pk[(size_t)gr * 4 + h])[0] = pj;
            }
        }
    }
}

// ---------------- CSR build ----------------
__global__ __launch_bounds__(256)
void count_deg(const int* __restrict__ ei, int E, int N,
               int* __restrict__ cnt_s, int* __restrict__ cnt_d)
{
    const int e = blockIdx.x * 256 + threadIdx.x;
    if (e >= E + N) return;
    int s, d;
    if (e < E) { s = ei[e]; d = ei[E + e]; } else { s = d = e - E; }
    atomicAdd(&cnt_s[s], 1);
    atomicAdd(&cnt_d[d], 1);
}

// grid.y = 0 (src) / 1 (dst)
__global__ __launch_bounds__(256)
void scan_part2(const int* __restrict__ cnt_s, const int* __restrict__ cnt_d,
                int* __restrict__ bsum_s, int* __restrict__ bsum_d, int n)
{
    const int* cnt = blockIdx.y ? cnt_d : cnt_s;
    int* bsum      = blockIdx.y ? bsum_d : bsum_s;
    __shared__ int sm[256];
    const int i = blockIdx.x * 256 + threadIdx.x;
    sm[threadIdx.x] = (i < n) ? cnt[i] : 0;
    __syncthreads();
    for (int s = 128; s > 0; s >>= 1) {
        if (threadIdx.x < s) sm[threadIdx.x] += sm[threadIdx.x + s];
        __syncthreads();
    }
    if (threadIdx.x == 0) bsum[blockIdx.x] = sm[0];
}

__global__ __launch_bounds__(1024)
void scan_bsums2(int* __restrict__ bsum_s, int* __restrict__ bsum_d, int nb)
{
    int* bsum = blockIdx.y ? bsum_d : bsum_s;
    __shared__ int sm[1024];
    const int i = threadIdx.x;
    if (i < nb) sm[i] = bsum[i];
    __syncthreads();
    if (i == 0) {
        int run = 0;
        for (int t = 0; t < nb; ++t) { int v = sm[t]; sm[t] = run; run += v; }
    }
    __syncthreads();
    if (i < nb) bsum[i] = sm[i];
}

// grid.y picks direction; also emits bucket tails (tail[b] = row[b<<8]).
__global__ __launch_bounds__(256)
void scan_final2(const int* __restrict__ cnt_s, const int* __restrict__ cnt_d,
                 const int* __restrict__ bsum_s, const int* __restrict__ bsum_d,
                 int* __restrict__ row_s, int* __restrict__ row_d,
                 int* __restrict__ tail_s, int* __restrict__ tail_d, int n)
{
    const int* cnt  = blockIdx.y ? cnt_d  : cnt_s;
    const int* bsum = blockIdx.y ? bsum_d : bsum_s;
    int* row        = blockIdx.y ? row_d  : row_s;
    int* tail       = blockIdx.y ? tail_d : tail_s;

    const int i = blockIdx.x * 256 + threadIdx.x;
    const int lane = threadIdx.x & 63, wid = threadIdx.x >> 6;
    int v = (i < n) ? cnt[i] : 0;
    int inc = v;
#pragma unroll
    for (int d = 1; d < 64; d <<= 1) {
        int y = __shfl_up(inc, d);
        if (lane >= d) inc += y;
    }
    __shared__ int wsum[4];
    if (lane == 63) wsum[wid] = inc;
    __syncthreads();
    int wofs = 0;
    for (int w = 0; w < wid; ++w) wofs += wsum[w];
    if (i < n) {
        const int r = inc - v + wofs + bsum[blockIdx.x];
        row[i] = r;
        if ((i & 255) == 0) tail[i >> 8] = r;   // bucket start
    }
}

// LDS-binned radix partition: per-WG chunk reservation -> CU-local contiguous writes.
__global__ __launch_bounds__(256)
void radix_scatter(const int* __restrict__ ei, int E, int N, int NB,
                   int* __restrict__ tail_s, int* __restrict__ tail_d,
                   int* __restrict__ bufs, int* __restrict__ bufd)
{
    __shared__ int cnt_s[512], cnt_d[512];
    const int base_e = blockIdx.x * SCAT_CHUNK;
    const int end_e  = min(base_e + SCAT_CHUNK, E + N);

    for (int i = threadIdx.x; i < NB; i += 256) { cnt_s[i] = 0; cnt_d[i] = 0; }
    __syncthreads();

    for (int e = base_e + threadIdx.x; e < end_e; e += 256) {
        int s, d;
        if (e < E) { s = ei[e]; d = ei[E + e]; } else { s = d = e - E; }
        atomicAdd(&cnt_s[s >> 8], 1);
        atomicAdd(&cnt_d[d >> 8], 1);
    }
    __syncthreads();

    for (int b = threadIdx.x; b < NB; b += 256) {
        const int c0 = cnt_s[b];
        cnt_s[b] = c0 ? atomicAdd(&tail_s[b], c0) : 0;
        const int c1 = cnt_d[b];
        cnt_d[b] = c1 ? atomicAdd(&tail_d[b], c1) : 0;
    }
    __syncthreads();

    for (int e = base_e + threadIdx.x; e < end_e; e += 256) {
        int s, d;
        if (e < E) { s = ei[e]; d = ei[E + e]; } else { s = d = e - E; }
        const int ps = atomicAdd(&cnt_s[s >> 8], 1);
        bufs[ps] = ((s & 255) << 17) | d;
        const int pd = atomicAdd(&cnt_d[d >> 8], 1);
        bufd[pd] = ((d & 255) << 17) | s;
    }
}

// One WG per bucket (grid.y = direction): place staged words into final CSR rows.
__global__ __launch_bounds__(256)
void bucket_place(const int* __restrict__ row_s, int* __restrict__ ent_s, const int* __restrict__ bufs,
                  const int* __restrict__ row_d, int* __restrict__ ent_d, const int* __restrict__ bufd,
                  int N, int NB, int EN)
{
    const int* __restrict__ row = (blockIdx.y == 0) ? row_s : row_d;
    int*       __restrict__ ent = (blockIdx.y == 0) ? ent_s : ent_d;
    const int* __restrict__ buf = (blockIdx.y == 0) ? bufs  : bufd;

    __shared__ int fc[256];
    const int node0 = blockIdx.x << 8;
    const int start = row[node0];
    const int nxt   = node0 + 256;
    const int end   = (nxt >= N) ? EN : row[nxt];

    fc[threadIdx.x] = 0;
    __syncthreads();

    for (int i = start + threadIdx.x; i < end; i += 256) {
        const unsigned w  = (unsigned)buf[i];
        const int loc  = (int)(w >> 17);
        const int slot = atomicAdd(&fc[loc], 1);
        ent[row[node0 | loc] + slot] = (int)(w & 0x1FFFFu);
    }
}

// Canonicalize each row ascending (wave bitonic, deg<=64; serial fallback).
// grid.y = direction.
__global__ __launch_bounds__(256)
void sort_rows_wave2(const int* __restrict__ row_s, int* __restrict__ ent_s,
                     const int* __restrict__ row_d, int* __restrict__ ent_d,
                     int N, int EN)
{
    const int* row = blockIdx.y ? row_d : row_s;
    int*       ent = blockIdx.y ? ent_d : ent_s;

    const int lane = threadIdx.x & 63;
    const int n    = blockIdx.x * 4 + (threadIdx.x >> 6);
    if (n >= N) return;
    const int lo  = row[n];
    const int hi  = (n == N - 1) ? EN : row[n + 1];
    const int deg = hi - lo;

    if (deg > 64) {
        if (lane == 0) {
            for (int i = lo + 1; i < hi; ++i) {
                int v = ent[i], j = i - 1;
                while (j >= lo && ent[j] > v) { ent[j + 1] = ent[j]; --j; }
                ent[j + 1] = v;
            }
        }
        return;
    }

    int v = (lane < deg) ? ent[lo + lane] : 0x7FFFFFFF;
#pragma unroll
    for (int k = 2; k <= 64; k <<= 1) {
#pragma unroll
        for (int j = k >> 1; j > 0; j >>= 1) {
            const int w  = __shfl_xor(v, j);
            const bool up   = ((lane & k) == 0);
            const bool lowr = ((lane & j) == 0);
            v = (lowr == up) ? min(v, w) : max(v, w);
        }
    }
    if (lane < deg) ent[lo + lane] = v;
}

// ---------------- segment softmax grouped by src (gather, no atomics) ------------
// One wave per src node: lane = slot(0..15) x head(0..3). alpha = ai[d] + aj[n].
// Single gather pass: per-slot alphas cached in registers (deg<=64 -> <=4/slot;
// exp(-inf)=0 pads exactly). Writes pk[n*4+h].y = max, .z = 1/(sum+eps).
__global__ __launch_bounds__(256)
void softmax_src(const int* __restrict__ row_s, const int* __restrict__ ent_s,
                 const float* __restrict__ ai, float4* __restrict__ pk, int N, int EN)
{
    const int lane = threadIdx.x & 63;
    const int n    = blockIdx.x * 4 + (threadIdx.x >> 6);
    if (n >= N) return;
    const int row = row_s[n];
    const int end = (n == N - 1) ? EN : row_s[n + 1];
    const int deg = end - row;
    const int slot = lane & 15, h = lane >> 4;
    const float ajh = ((const float*)&pk[(size_t)n * 4 + h])[0];

    float m, ssum;
    if (deg <= 64) {
        float a0 = -INFINITY, a1 = -INFINITY, a2 = -INFINITY, a3 = -INFINITY;
        int t = row + slot;
        if (t < end) { a0 = LRELU_ATT(ai[(size_t)ent_s[t] * 4 + h] + ajh); t += 16; }
        if (t < end) { a1 = LRELU_ATT(ai[(size_t)ent_s[t] * 4 + h] + ajh); t += 16; }
        if (t < end) { a2 = LRELU_ATT(ai[(size_t)ent_s[t] * 4 + h] + ajh); t += 16; }
        if (t < end) { a3 = LRELU_ATT(ai[(size_t)ent_s[t] * 4 + h] + ajh); }
        m = fmaxf(fmaxf(a0, a1), fmaxf(a2, a3));
#pragma unroll
        for (int mm = 1; mm < 16; mm <<= 1) m = fmaxf(m, __shfl_xor(m, mm));
        ssum = __expf(a0 - m);      // exp(-inf - m) == 0 for padded slots
        ssum += __expf(a1 - m);
        ssum += __expf(a2 - m);
        ssum += __expf(a3 - m);
#pragma unroll
        for (int mm = 1; mm < 16; mm <<= 1) ssum += __shfl_xor(ssum, mm);
    } else {
        m = -INFINITY;
        for (int t = row + slot; t < end; t += 16) {
            const int d = ent_s[t];
            const float a = LRELU_ATT(ai[(size_t)d * 4 + h] + ajh);
            m = fmaxf(m, a);
        }
#pragma unroll
        for (int mm = 1; mm < 16; mm <<= 1) m = fmaxf(m, __shfl_xor(m, mm));
        ssum = 0.f;
        for (int t = row + slot; t < end; t += 16) {
            const int d = ent_s[t];
            const float a = LRELU_ATT(ai[(size_t)d * 4 + h] + ajh);
            ssum += __expf(a - m);
        }
#pragma unroll
        for (int mm = 1; mm < 16; mm <<= 1) ssum += __shfl_xor(ssum, mm);
    }

    if (slot == 0) {
        float* p = (float*)&pk[(size_t)n * 4 + h];
        p[1] = m;
        p[2] = 1.f / (ssum + 1e-16f);
    }
}

// ---------------- aggregation by dst (gather, no atomics), fused bias+relu -------
// 2 dst-nodes per wave (half-wave = 32 lanes x float4 = one 512B H row), 4-way
// unrolled with int4 index loads. Strict t-order accumulation per row.
__global__ __launch_bounds__(256)
void aggregate_dst(const int* __restrict__ row_d, const int* __restrict__ ent_d,
                   const float* __restrict__ ai, const float4* __restrict__ pk,
                   const float* __restrict__ H, const float* __restrict__ bias,
                   float* __restrict__ OUT, int N, int EN)
{
    const int lane = threadIdx.x & 63;
    const int half = lane >> 5, ll = lane & 31;
    const int n    = blockIdx.x * 8 + (threadIdx.x >> 6) * 2 + half;
    if (n >= N) return;
    const int row = row_d[n];
    const int end = (n == N - 1) ? EN : row_d[n + 1];
    const int h   = ll >> 3;                    // features [4ll,4ll+4) -> head
    const float aih = ai[(size_t)n * 4 + h];

    float4 acc = make_float4(0.f, 0.f, 0.f, 0.f);
    int t = row;
    const int astart = min((row + 3) & ~3, end);    // align for int4 loads
    for (; t < astart; ++t) {
        const int s = ent_d[t];
        const float4 hv = *reinterpret_cast<const float4*>(&H[(size_t)s * 128 + ll * 4]);
        const float4 pv = pk[(size_t)s * 4 + h];
        const float c   = __expf(LRELU_ATT(aih + pv.x) - pv.y) * pv.z;
        acc.x = fmaf(hv.x, c, acc.x); acc.y = fmaf(hv.y, c, acc.y);
        acc.z = fmaf(hv.z, c, acc.z); acc.w = fmaf(hv.w, c, acc.w);
    }
    for (; t + 4 <= end; t += 4) {
        const int4 sv = *reinterpret_cast<const int4*>(&ent_d[t]);

        const float4 h0 = *reinterpret_cast<const float4*>(&H[(size_t)sv.x * 128 + ll * 4]);
        const float4 h1 = *reinterpret_cast<const float4*>(&H[(size_t)sv.y * 128 + ll * 4]);
        const float4 h2 = *reinterpret_cast<const float4*>(&H[(size_t)sv.z * 128 + ll * 4]);
        const float4 h3 = *reinterpret_cast<const float4*>(&H[(size_t)sv.w * 128 + ll * 4]);

        const float4 p0 = pk[(size_t)sv.x * 4 + h];
        const float4 p1 = pk[(size_t)sv.y * 4 + h];
        const float4 p2 = pk[(size_t)sv.z * 4 + h];
        const float4 p3 = pk[(size_t)sv.w * 4 + h];

        const float c0 = __expf(LRELU_ATT(aih + p0.x) - p0.y) * p0.z;
        const float c1 = __expf(LRELU_ATT(aih + p1.x) - p1.y) * p1.z;
        const float c2 = __expf(LRELU_ATT(aih + p2.x) - p2.y) * p2.z;
        const float c3 = __expf(LRELU_ATT(aih + p3.x) - p3.y) * p3.z;

        acc.x = fmaf(h0.x, c0, acc.x); acc.y = fmaf(h0.y, c0, acc.y);
        acc.z = fmaf(h0.z, c0, acc.z); acc.w = fmaf(h0.w, c0, acc.w);
        acc.x = fmaf(h1.x, c1, acc.x); acc.y = fmaf(h1.y, c1, acc.y);
        acc.z = fmaf(h1.z, c1, acc.z); acc.w = fmaf(h1.w, c1, acc.w);
        acc.x = fmaf(h2.x, c2, acc.x); acc.y = fmaf(h2.y, c2, acc.y);
        acc.z = fmaf(h2.z, c2, acc.z); acc.w = fmaf(h2.w, c2, acc.w);
        acc.x = fmaf(h3.x, c3, acc.x); acc.y = fmaf(h3.y, c3, acc.y);
        acc.z = fmaf(h3.z, c3, acc.z); acc.w = fmaf(h3.w, c3, acc.w);
    }
    for (; t < end; ++t) {
        const int s = ent_d[t];
        const float4 hv = *reinterpret_cast<const float4*>(&H[(size_t)s * 128 + ll * 4]);
        const float4 pv = pk[(size_t)s * 4 + h];
        const float c   = __expf(LRELU_ATT(aih + pv.x) - pv.y) * pv.z;
        acc.x = fmaf(hv.x, c, acc.x); acc.y = fmaf(hv.y, c, acc.y);
        acc.z = fmaf(hv.z, c, acc.z); acc.w = fmaf(hv.w, c, acc.w);
    }
    const float4 bv = *reinterpret_cast<const float4*>(&bias[ll * 4]);
    float4 o;
    o.x = fmaxf(acc.x + bv.x, 0.f);
    o.y = fmaxf(acc.y + bv.y, 0.f);
    o.z = fmaxf(acc.z + bv.z, 0.f);
    o.w = fmaxf(acc.w + bv.w, 0.f);
    *reinterpret_cast<float4*>(&OUT[(size_t)n * 128 + ll * 4]) = o;
}

// ---------------- output head ----------------
__global__ __launch_bounds__(256)
void out_kernel(const float* __restrict__ G, const float* __restrict__ oW,
                float* __restrict__ out3, float* __restrict__ ypredF, int N)
{
    __shared__ float w[384];
    for (int i = threadIdx.x; i < 384; i += 256) w[i] = oW[i];
    __syncthreads();
    const int n = blockIdx.x * 256 + threadIdx.x;
    if (n >= N) return;
    const float* g = G + (size_t)n * 128;
    float a0 = 0.f, a1 = 0.f, a2 = 0.f;
    for (int k = 0; k < 128; k += 4) {
        float4 gv = *reinterpret_cast<const float4*>(&g[k]);
        a0 = fmaf(gv.x, w[(k+0)*3+0], a0); a1 = fmaf(gv.x, w[(k+0)*3+1], a1); a2 = fmaf(gv.x, w[(k+0)*3+2], a2);
        a0 = fmaf(gv.y, w[(k+1)*3+0], a0); a1 = fmaf(gv.y, w[(k+1)*3+1], a1); a2 = fmaf(gv.y, w[(k+1)*3+2], a2);
        a0 = fmaf(gv.z, w[(k+2)*3+0], a0); a1 = fmaf(gv.z, w[(k+2)*3+1], a1); a2 = fmaf(gv.z, w[(k+2)*3+2], a2);
        a0 = fmaf(gv.w, w[(k+3)*3+0], a0); a1 = fmaf(gv.w, w[(k+3)*3+1], a1); a2 = fmaf(gv.w, w[(k+3)*3+2], a2);
    }
    out3[(size_t)n * 3 + 0] = a0;
    out3[(size_t)n * 3 + 1] = a1;
    out3[(size_t)n * 3 + 2] = a2;
    int idx = 0; float best = a0;
    if (a1 > best) { best = a1; idx = 1; }
    if (a2 > best) { best = a2; idx = 2; }
    ypredF[n] = (float)idx;
}

__global__ __launch_bounds__(256)
void gather_kernel(const int* __restrict__ nix, const float* __restrict__ out3,
                   const float* __restrict__ ypredF, float* __restrict__ nodeOut,
                   float* __restrict__ ynode, int M)
{
    const int i = blockIdx.x * 256 + threadIdx.x;
    if (i >= M) return;
    const int n = nix[i];
    nodeOut[(size_t)i * 3 + 0] = out3[(size_t)n * 3 + 0];
    nodeOut[(size_t)i * 3 + 1] = out3[(size_t)n * 3 + 1];
    nodeOut[(size_t)i * 3 + 2] = out3[(size_t)n * 3 + 2];
    ynode[i] = ypredF[n];
}

extern "C" void kernel_launch(void* const* d_in, const int* in_sizes, int n_in,
                              void* d_out, int out_size, void* d_ws, size_t ws_size,
                              hipStream_t stream)
{
    const float* x      = (const float*)d_in[0];
    const int*   ei     = (const int*)d_in[1];
    const int*   nodeix = (const int*)d_in[2];
    const float* phW    = (const float*)d_in[3];
    const float* phb    = (const float*)d_in[4];
    const float* Wl[3]   = {(const float*)d_in[5],  (const float*)d_in[9],  (const float*)d_in[13]};
    const float* bl[3]   = {(const float*)d_in[6],  (const float*)d_in[10], (const float*)d_in[14]};
    const float* attl[3] = {(const float*)d_in[7],  (const float*)d_in[11], (const float*)d_in[15]};
    const float* bsl[3]  = {(const float*)d_in[8],  (const float*)d_in[12], (const float*)d_in[16]};
    const float* outW    = (const float*)d_in[17];

    const int N  = in_sizes[0] / 256;
    const int E  = in_sizes[1] / 2;
    const int M  = in_sizes[2];
    const int EN = E + N;
    const int NB  = (N + 255) >> 8;         // 256-node buckets (<=512 for N<=131072)
    const int NB4 = (NB + 3) & ~3;          // padded so ent_* stay 16B-aligned

    // ---- workspace layout ----
    float*  P     = (float*)d_ws;                     // N*128
    float*  Q     = P + (size_t)N * 128;              // N*128 (aliased as CSR staging)
    float*  ai    = Q + (size_t)N * 128;              // N*4
    float4* pk    = (float4*)(ai + (size_t)N * 4);    // N*4 float4 {aj, amax, rden, -}
    float*  out3  = (float*)(pk + (size_t)N * 4);     // N*3 (pad to N*4 for alignment)
    int* row_s   = (int*)(out3 + (size_t)N * 4);      // N
    int* row_d   = row_s + N;                         // N
    int* cnt_s   = row_d + N;                         // N (degree histogram)
    int* cnt_d   = cnt_s + N;                         // N
    int* tail_s  = cnt_d + N;                         // NB4 (bucket tails, padded)
    int* tail_d  = tail_s + NB4;                      // NB4
    int* bsum_s  = tail_d + NB4;                      // 1024
    int* bsum_d  = bsum_s + 1024;                     // 1024
    int* ent_s   = bsum_d + 1024;                     // EN (16B-aligned for N%4==0)
    int* ent_d   = ent_s + (size_t)EN;                // EN

    // staging buffers alias Q (unused until the first GEMM): 2*EN ints <= N*128 floats
    int* bufA_s = (int*)Q;
    int* bufA_d = bufA_s + (size_t)EN;

    // ---- d_out layout: x_embed[N*128] node_output[M*3] ypred[N] y_nodepred[M]
    float* o_embed   = (float*)d_out;
    float* o_nodeout = o_embed + (size_t)N * 128;
    float* o_ypred   = o_nodeout + (size_t)M * 3;
    float* o_ynode   = o_ypred + N;

    const int nb = (N + 255) / 256;
    const int ng = (N + 127) / 128;   // GEMM grid

    // ---- CSR build (once; reused by all 3 layers) ----
    hipMemsetAsync(cnt_s, 0, (size_t)2 * N * sizeof(int), stream);
    count_deg<<<(EN + 255) / 256, 256, 0, stream>>>(ei, E, N, cnt_s, cnt_d);
    scan_part2<<<dim3(nb, 2), 256, 0, stream>>>(cnt_s, cnt_d, bsum_s, bsum_d, N);
    scan_bsums2<<<dim3(1, 2), 1024, 0, stream>>>(bsum_s, bsum_d, nb);
    scan_final2<<<dim3(nb, 2), 256, 0, stream>>>(cnt_s, cnt_d, bsum_s, bsum_d,
                                                 row_s, row_d, tail_s, tail_d, N);
    radix_scatter<<<(EN + SCAT_CHUNK - 1) / SCAT_CHUNK, 256, 0, stream>>>(
        ei, E, N, NB, tail_s, tail_d, bufA_s, bufA_d);
    bucket_place<<<dim3(NB, 2), 256, 0, stream>>>(row_s, ent_s, bufA_s,
                                                  row_d, ent_d, bufA_d, N, NB, EN);
    sort_rows_wave2<<<dim3((N + 3) / 4, 2), 256, 0, stream>>>(row_s, ent_s, row_d, ent_d, N, EN);

    // ---- pheno transform: P = x @ phW + phb ----
    gemm_tile<256, false><<<ng, 256, 0, stream>>>(x, phW, phb, P, nullptr, nullptr, nullptr, N);

    // ---- 3 GAT layers ----
    for (int l = 0; l < 3; ++l) {
        float* tgt = (l == 2) ? o_embed : P;   // layer 3 writes x_embed directly
        gemm_tile<128, true><<<ng, 256, 0, stream>>>(P, Wl[l], bl[l], Q, attl[l], ai, pk, N);
        softmax_src<<<(N + 3) / 4, 256, 0, stream>>>(row_s, ent_s, ai, pk, N, EN);
        aggregate_dst<<<(N + 7) / 8, 256, 0, stream>>>(row_d, ent_d, ai, pk,
                                                       Q, bsl[l], tgt, N, EN);
    }

    out_kernel<<<(N + 255) / 256, 256, 0, stream>>>(o_embed, outW, out3, o_ypred, N);
    gather_kernel<<<(M + 255) / 256, 256, 0, stream>>>(nodeix, out3, o_ypred, o_nodeout, o_ynode, M);
}

// Round 14
// 1089.032 us; speedup vs baseline: 1.9812x; 1.0090x over previous
//
#include <hip/hip_runtime.h>
#include <math.h>

// GIG_GAT: pheno GEMM + 3x GATConv with CSR-gather aggregation (no feature atomics),
// CSR-gather segment softmax (no atomics), fused bias+relu epilogue. All fp32.
// CSR build: count/scan (paired via grid.y, tails fused) -> LDS-binned radix
// partition -> per-bucket place -> wave-bitonic row sort (canonical order ->
// deterministic float accumulation). Attention dots fused into GEMM epilogue.
// aggregate_dst: 2 dst-nodes/wave (float4/lane), 8-way unrolled main loop
// (8 H-rows in flight per half-wave), launch_bounds-guarded occupancy.

#define LRELU_ATT(v) ((v) >= 0.f ? (v) : 0.2f * (v))
#define SCAT_CHUNK 8192

// ---------------- GEMM: Y[N,128] = X[N,K] @ W[K,128] + b (+ fused att dots) ------
template <int K, bool DOTS>
__global__ __launch_bounds__(256)
void gemm_tile(const float* __restrict__ X, const float* __restrict__ W,
               const float* __restrict__ bvec, float* __restrict__ Y,
               const float* __restrict__ att, float* __restrict__ ai,
               float4* __restrict__ pk, int N)
{
    __shared__ __align__(16) float xt[32][132];   // [k][row], padded stride
    __shared__ __align__(16) float ws[32][132];   // [k][col], padded stride

    const int t  = threadIdx.x;
    const int tx = t & 15, ty = t >> 4;
    const int r0 = blockIdx.x * 128;

    float acc[8][8];
#pragma unroll
    for (int i = 0; i < 8; ++i)
#pragma unroll
        for (int j = 0; j < 8; ++j) acc[i][j] = 0.f;

    const int srow = t >> 3;          // X stage: 32 rows per pass
    const int sk4  = (t & 7) * 4;
    const int wkr  = t >> 5;          // W stage: 8 k-rows per pass
    const int wc4  = (t & 31) * 4;

    for (int kc = 0; kc < K; kc += 32) {
#pragma unroll
        for (int p = 0; p < 4; ++p) {
            const int r  = srow + p * 32;
            const int gr = r0 + r;
            float4 v = make_float4(0.f, 0.f, 0.f, 0.f);
            if (gr < N) v = *reinterpret_cast<const float4*>(&X[(size_t)gr * K + kc + sk4]);
            xt[sk4 + 0][r] = v.x; xt[sk4 + 1][r] = v.y;
            xt[sk4 + 2][r] = v.z; xt[sk4 + 3][r] = v.w;
        }
#pragma unroll
        for (int p = 0; p < 4; ++p) {
            const int k = wkr + p * 8;
            float4 v = *reinterpret_cast<const float4*>(&W[(size_t)(kc + k) * 128 + wc4]);
            *reinterpret_cast<float4*>(&ws[k][wc4]) = v;
        }
        __syncthreads();

#pragma unroll
        for (int k = 0; k < 32; ++k) {
            const float4 a0 = *reinterpret_cast<const float4*>(&xt[k][8 * ty]);
            const float4 a1 = *reinterpret_cast<const float4*>(&xt[k][8 * ty + 4]);
            const float4 b0 = *reinterpret_cast<const float4*>(&ws[k][8 * tx]);
            const float4 b1 = *reinterpret_cast<const float4*>(&ws[k][8 * tx + 4]);
            const float av[8] = {a0.x, a0.y, a0.z, a0.w, a1.x, a1.y, a1.z, a1.w};
            const float bv[8] = {b0.x, b0.y, b0.z, b0.w, b1.x, b1.y, b1.z, b1.w};
#pragma unroll
            for (int i = 0; i < 8; ++i)
#pragma unroll
                for (int j = 0; j < 8; ++j)
                    acc[i][j] = fmaf(av[i], bv[j], acc[i][j]);
        }
        __syncthreads();
    }

    const float4 bb0 = *reinterpret_cast<const float4*>(&bvec[8 * tx]);
    const float4 bb1 = *reinterpret_cast<const float4*>(&bvec[8 * tx + 4]);

    const int h  = tx >> 2;
    const int k0 = (8 * tx) & 31;
    float4 ati0, ati1, atj0, atj1;
    if (DOTS) {
        ati0 = *reinterpret_cast<const float4*>(&att[h * 64 + k0]);
        ati1 = *reinterpret_cast<const float4*>(&att[h * 64 + k0 + 4]);
        atj0 = *reinterpret_cast<const float4*>(&att[h * 64 + 32 + k0]);
        atj1 = *reinterpret_cast<const float4*>(&att[h * 64 + 32 + k0 + 4]);
    }

#pragma unroll
    for (int i = 0; i < 8; ++i) {
        const int gr = r0 + 8 * ty + i;
        float4 o0 = make_float4(acc[i][0] + bb0.x, acc[i][1] + bb0.y,
                                acc[i][2] + bb0.z, acc[i][3] + bb0.w);
        float4 o1 = make_float4(acc[i][4] + bb1.x, acc[i][5] + bb1.y,
                                acc[i][6] + bb1.z, acc[i][7] + bb1.w);
        if (gr < N) {
            *reinterpret_cast<float4*>(&Y[(size_t)gr * 128 + 8 * tx])     = o0;
            *reinterpret_cast<float4*>(&Y[(size_t)gr * 128 + 8 * tx + 4]) = o1;
        }
        if (DOTS) {
            float pi = o0.x * ati0.x + o0.y * ati0.y + o0.z * ati0.z + o0.w * ati0.w
                     + o1.x * ati1.x + o1.y * ati1.y + o1.z * ati1.z + o1.w * ati1.w;
            float pj = o0.x * atj0.x + o0.y * atj0.y + o0.z * atj0.z + o0.w * atj0.w
                     + o1.x * atj1.x + o1.y * atj1.y + o1.z * atj1.z + o1.w * atj1.w;
            pi += __shfl_xor(pi, 1); pi += __shfl_xor(pi, 2);
            pj += __shfl_xor(pj, 1); pj += __shfl_xor(pj, 2);
            if ((tx & 3) == 0 && gr < N) {
                ai[(size_t)gr * 4 + h] = pi;
                ((float*)&pk[(size_t)gr * 4 + h])[0] = pj;
            }
        }
    }
}

// ---------------- CSR build ----------------
__global__ __launch_bounds__(256)
void count_deg(const int* __restrict__ ei, int E, int N,
               int* __restrict__ cnt_s, int* __restrict__ cnt_d)
{
    const int e = blockIdx.x * 256 + threadIdx.x;
    if (e >= E + N) return;
    int s, d;
    if (e < E) { s = ei[e]; d = ei[E + e]; } else { s = d = e - E; }
    atomicAdd(&cnt_s[s], 1);
    atomicAdd(&cnt_d[d], 1);
}

// grid.y = 0 (src) / 1 (dst)
__global__ __launch_bounds__(256)
void scan_part2(const int* __restrict__ cnt_s, const int* __restrict__ cnt_d,
                int* __restrict__ bsum_s, int* __restrict__ bsum_d, int n)
{
    const int* cnt = blockIdx.y ? cnt_d : cnt_s;
    int* bsum      = blockIdx.y ? bsum_d : bsum_s;
    __shared__ int sm[256];
    const int i = blockIdx.x * 256 + threadIdx.x;
    sm[threadIdx.x] = (i < n) ? cnt[i] : 0;
    __syncthreads();
    for (int s = 128; s > 0; s >>= 1) {
        if (threadIdx.x < s) sm[threadIdx.x] += sm[threadIdx.x + s];
        __syncthreads();
    }
    if (threadIdx.x == 0) bsum[blockIdx.x] = sm[0];
}

__global__ __launch_bounds__(1024)
void scan_bsums2(int* __restrict__ bsum_s, int* __restrict__ bsum_d, int nb)
{
    int* bsum = blockIdx.y ? bsum_d : bsum_s;
    __shared__ int sm[1024];
    const int i = threadIdx.x;
    if (i < nb) sm[i] = bsum[i];
    __syncthreads();
    if (i == 0) {
        int run = 0;
        for (int t = 0; t < nb; ++t) { int v = sm[t]; sm[t] = run; run += v; }
    }
    __syncthreads();
    if (i < nb) bsum[i] = sm[i];
}

// grid.y picks direction; also emits bucket tails (tail[b] = row[b<<8]).
__global__ __launch_bounds__(256)
void scan_final2(const int* __restrict__ cnt_s, const int* __restrict__ cnt_d,
                 const int* __restrict__ bsum_s, const int* __restrict__ bsum_d,
                 int* __restrict__ row_s, int* __restrict__ row_d,
                 int* __restrict__ tail_s, int* __restrict__ tail_d, int n)
{
    const int* cnt  = blockIdx.y ? cnt_d  : cnt_s;
    const int* bsum = blockIdx.y ? bsum_d : bsum_s;
    int* row        = blockIdx.y ? row_d  : row_s;
    int* tail       = blockIdx.y ? tail_d : tail_s;

    const int i = blockIdx.x * 256 + threadIdx.x;
    const int lane = threadIdx.x & 63, wid = threadIdx.x >> 6;
    int v = (i < n) ? cnt[i] : 0;
    int inc = v;
#pragma unroll
    for (int d = 1; d < 64; d <<= 1) {
        int y = __shfl_up(inc, d);
        if (lane >= d) inc += y;
    }
    __shared__ int wsum[4];
    if (lane == 63) wsum[wid] = inc;
    __syncthreads();
    int wofs = 0;
    for (int w = 0; w < wid; ++w) wofs += wsum[w];
    if (i < n) {
        const int r = inc - v + wofs + bsum[blockIdx.x];
        row[i] = r;
        if ((i & 255) == 0) tail[i >> 8] = r;   // bucket start
    }
}

// LDS-binned radix partition: per-WG chunk reservation -> CU-local contiguous writes.
__global__ __launch_bounds__(256)
void radix_scatter(const int* __restrict__ ei, int E, int N, int NB,
                   int* __restrict__ tail_s, int* __restrict__ tail_d,
                   int* __restrict__ bufs, int* __restrict__ bufd)
{
    __shared__ int cnt_s[512], cnt_d[512];
    const int base_e = blockIdx.x * SCAT_CHUNK;
    const int end_e  = min(base_e + SCAT_CHUNK, E + N);

    for (int i = threadIdx.x; i < NB; i += 256) { cnt_s[i] = 0; cnt_d[i] = 0; }
    __syncthreads();

    for (int e = base_e + threadIdx.x; e < end_e; e += 256) {
        int s, d;
        if (e < E) { s = ei[e]; d = ei[E + e]; } else { s = d = e - E; }
        atomicAdd(&cnt_s[s >> 8], 1);
        atomicAdd(&cnt_d[d >> 8], 1);
    }
    __syncthreads();

    for (int b = threadIdx.x; b < NB; b += 256) {
        const int c0 = cnt_s[b];
        cnt_s[b] = c0 ? atomicAdd(&tail_s[b], c0) : 0;
        const int c1 = cnt_d[b];
        cnt_d[b] = c1 ? atomicAdd(&tail_d[b], c1) : 0;
    }
    __syncthreads();

    for (int e = base_e + threadIdx.x; e < end_e; e += 256) {
        int s, d;
        if (e < E) { s = ei[e]; d = ei[E + e]; } else { s = d = e - E; }
        const int ps = atomicAdd(&cnt_s[s >> 8], 1);
        bufs[ps] = ((s & 255) << 17) | d;
        const int pd = atomicAdd(&cnt_d[d >> 8], 1);
        bufd[pd] = ((d & 255) << 17) | s;
    }
}

// One WG per bucket (grid.y = direction): place staged words into final CSR rows.
__global__ __launch_bounds__(256)
void bucket_place(const int* __restrict__ row_s, int* __restrict__ ent_s, const int* __restrict__ bufs,
                  const int* __restrict__ row_d, int* __restrict__ ent_d, const int* __restrict__ bufd,
                  int N, int NB, int EN)
{
    const int* __restrict__ row = (blockIdx.y == 0) ? row_s : row_d;
    int*       __restrict__ ent = (blockIdx.y == 0) ? ent_s : ent_d;
    const int* __restrict__ buf = (blockIdx.y == 0) ? bufs  : bufd;

    __shared__ int fc[256];
    const int node0 = blockIdx.x << 8;
    const int start = row[node0];
    const int nxt   = node0 + 256;
    const int end   = (nxt >= N) ? EN : row[nxt];

    fc[threadIdx.x] = 0;
    __syncthreads();

    for (int i = start + threadIdx.x; i < end; i += 256) {
        const unsigned w  = (unsigned)buf[i];
        const int loc  = (int)(w >> 17);
        const int slot = atomicAdd(&fc[loc], 1);
        ent[row[node0 | loc] + slot] = (int)(w & 0x1FFFFu);
    }
}

// Canonicalize each row ascending (wave bitonic, deg<=64; serial fallback).
__global__ __launch_bounds__(256)
void sort_rows_wave2(const int* __restrict__ row_s, int* __restrict__ ent_s,
                     const int* __restrict__ row_d, int* __restrict__ ent_d,
                     int N, int EN)
{
    const int* row = blockIdx.y ? row_d : row_s;
    int*       ent = blockIdx.y ? ent_d : ent_s;

    const int lane = threadIdx.x & 63;
    const int n    = blockIdx.x * 4 + (threadIdx.x >> 6);
    if (n >= N) return;
    const int lo  = row[n];
    const int hi  = (n == N - 1) ? EN : row[n + 1];
    const int deg = hi - lo;

    if (deg > 64) {
        if (lane == 0) {
            for (int i = lo + 1; i < hi; ++i) {
                int v = ent[i], j = i - 1;
                while (j >= lo && ent[j] > v) { ent[j + 1] = ent[j]; --j; }
                ent[j + 1] = v;
            }
        }
        return;
    }

    int v = (lane < deg) ? ent[lo + lane] : 0x7FFFFFFF;
#pragma unroll
    for (int k = 2; k <= 64; k <<= 1) {
#pragma unroll
        for (int j = k >> 1; j > 0; j >>= 1) {
            const int w  = __shfl_xor(v, j);
            const bool up   = ((lane & k) == 0);
            const bool lowr = ((lane & j) == 0);
            v = (lowr == up) ? min(v, w) : max(v, w);
        }
    }
    if (lane < deg) ent[lo + lane] = v;
}

// ---------------- segment softmax grouped by src (gather, no atomics) ------------
__global__ __launch_bounds__(256)
void softmax_src(const int* __restrict__ row_s, const int* __restrict__ ent_s,
                 const float* __restrict__ ai, float4* __restrict__ pk, int N, int EN)
{
    const int lane = threadIdx.x & 63;
    const int n    = blockIdx.x * 4 + (threadIdx.x >> 6);
    if (n >= N) return;
    const int row = row_s[n];
    const int end = (n == N - 1) ? EN : row_s[n + 1];
    const int deg = end - row;
    const int slot = lane & 15, h = lane >> 4;
    const float ajh = ((const float*)&pk[(size_t)n * 4 + h])[0];

    float m, ssum;
    if (deg <= 64) {
        float a0 = -INFINITY, a1 = -INFINITY, a2 = -INFINITY, a3 = -INFINITY;
        int t = row + slot;
        if (t < end) { a0 = LRELU_ATT(ai[(size_t)ent_s[t] * 4 + h] + ajh); t += 16; }
        if (t < end) { a1 = LRELU_ATT(ai[(size_t)ent_s[t] * 4 + h] + ajh); t += 16; }
        if (t < end) { a2 = LRELU_ATT(ai[(size_t)ent_s[t] * 4 + h] + ajh); t += 16; }
        if (t < end) { a3 = LRELU_ATT(ai[(size_t)ent_s[t] * 4 + h] + ajh); }
        m = fmaxf(fmaxf(a0, a1), fmaxf(a2, a3));
#pragma unroll
        for (int mm = 1; mm < 16; mm <<= 1) m = fmaxf(m, __shfl_xor(m, mm));
        ssum = __expf(a0 - m);      // exp(-inf - m) == 0 for padded slots
        ssum += __expf(a1 - m);
        ssum += __expf(a2 - m);
        ssum += __expf(a3 - m);
#pragma unroll
        for (int mm = 1; mm < 16; mm <<= 1) ssum += __shfl_xor(ssum, mm);
    } else {
        m = -INFINITY;
        for (int t = row + slot; t < end; t += 16) {
            const int d = ent_s[t];
            const float a = LRELU_ATT(ai[(size_t)d * 4 + h] + ajh);
            m = fmaxf(m, a);
        }
#pragma unroll
        for (int mm = 1; mm < 16; mm <<= 1) m = fmaxf(m, __shfl_xor(m, mm));
        ssum = 0.f;
        for (int t = row + slot; t < end; t += 16) {
            const int d = ent_s[t];
            const float a = LRELU_ATT(ai[(size_t)d * 4 + h] + ajh);
            ssum += __expf(a - m);
        }
#pragma unroll
        for (int mm = 1; mm < 16; mm <<= 1) ssum += __shfl_xor(ssum, mm);
    }

    if (slot == 0) {
        float* p = (float*)&pk[(size_t)n * 4 + h];
        p[1] = m;
        p[2] = 1.f / (ssum + 1e-16f);
    }
}

// ---------------- aggregation by dst (gather, no atomics), fused bias+relu -------
// 2 dst-nodes per wave (half-wave = 32 lanes x float4 = one 512B H row).
// 8-way unrolled main loop: 8 H-rows in flight per half-wave (MLP x2 vs 4-way);
// pk handled in two 4-blocks with eager coef computation to cap live VGPRs.
// Strict t-order accumulation per row (determinism + identical rounding).
__global__ __launch_bounds__(256, 6)
void aggregate_dst(const int* __restrict__ row_d, const int* __restrict__ ent_d,
                   const float* __restrict__ ai, const float4* __restrict__ pk,
                   const float* __restrict__ H, const float* __restrict__ bias,
                   float* __restrict__ OUT, int N, int EN)
{
    const int lane = threadIdx.x & 63;
    const int half = lane >> 5, ll = lane & 31;
    const int n    = blockIdx.x * 8 + (threadIdx.x >> 6) * 2 + half;
    if (n >= N) return;
    const int row = row_d[n];
    const int end = (n == N - 1) ? EN : row_d[n + 1];
    const int h   = ll >> 3;                    // features [4ll,4ll+4) -> head
    const float aih = ai[(size_t)n * 4 + h];

    float4 acc = make_float4(0.f, 0.f, 0.f, 0.f);
    int t = row;
    const int astart = min((row + 3) & ~3, end);    // align for int4 loads
    for (; t < astart; ++t) {
        const int s = ent_d[t];
        const float4 hv = *reinterpret_cast<const float4*>(&H[(size_t)s * 128 + ll * 4]);
        const float4 pv = pk[(size_t)s * 4 + h];
        const float c   = __expf(LRELU_ATT(aih + pv.x) - pv.y) * pv.z;
        acc.x = fmaf(hv.x, c, acc.x); acc.y = fmaf(hv.y, c, acc.y);
        acc.z = fmaf(hv.z, c, acc.z); acc.w = fmaf(hv.w, c, acc.w);
    }
    // 8-wide: issue all 8 H loads up front, pk/coef in two 4-blocks
    for (; t + 8 <= end; t += 8) {
        const int4 sa = *reinterpret_cast<const int4*>(&ent_d[t]);
        const int4 sb = *reinterpret_cast<const int4*>(&ent_d[t + 4]);

        const float4 h0 = *reinterpret_cast<const float4*>(&H[(size_t)sa.x * 128 + ll * 4]);
        const float4 h1 = *reinterpret_cast<const float4*>(&H[(size_t)sa.y * 128 + ll * 4]);
        const float4 h2 = *reinterpret_cast<const float4*>(&H[(size_t)sa.z * 128 + ll * 4]);
        const float4 h3 = *reinterpret_cast<const float4*>(&H[(size_t)sa.w * 128 + ll * 4]);
        const float4 h4 = *reinterpret_cast<const float4*>(&H[(size_t)sb.x * 128 + ll * 4]);
        const float4 h5 = *reinterpret_cast<const float4*>(&H[(size_t)sb.y * 128 + ll * 4]);
        const float4 h6 = *reinterpret_cast<const float4*>(&H[(size_t)sb.z * 128 + ll * 4]);
        const float4 h7 = *reinterpret_cast<const float4*>(&H[(size_t)sb.w * 128 + ll * 4]);

        const float4 p0 = pk[(size_t)sa.x * 4 + h];
        const float4 p1 = pk[(size_t)sa.y * 4 + h];
        const float4 p2 = pk[(size_t)sa.z * 4 + h];
        const float4 p3 = pk[(size_t)sa.w * 4 + h];
        const float c0 = __expf(LRELU_ATT(aih + p0.x) - p0.y) * p0.z;
        const float c1 = __expf(LRELU_ATT(aih + p1.x) - p1.y) * p1.z;
        const float c2 = __expf(LRELU_ATT(aih + p2.x) - p2.y) * p2.z;
        const float c3 = __expf(LRELU_ATT(aih + p3.x) - p3.y) * p3.z;

        const float4 p4 = pk[(size_t)sb.x * 4 + h];
        const float4 p5 = pk[(size_t)sb.y * 4 + h];
        const float4 p6 = pk[(size_t)sb.z * 4 + h];
        const float4 p7 = pk[(size_t)sb.w * 4 + h];
        const float c4 = __expf(LRELU_ATT(aih + p4.x) - p4.y) * p4.z;
        const float c5 = __expf(LRELU_ATT(aih + p5.x) - p5.y) * p5.z;
        const float c6 = __expf(LRELU_ATT(aih + p6.x) - p6.y) * p6.z;
        const float c7 = __expf(LRELU_ATT(aih + p7.x) - p7.y) * p7.z;

        acc.x = fmaf(h0.x, c0, acc.x); acc.y = fmaf(h0.y, c0, acc.y);
        acc.z = fmaf(h0.z, c0, acc.z); acc.w = fmaf(h0.w, c0, acc.w);
        acc.x = fmaf(h1.x, c1, acc.x); acc.y = fmaf(h1.y, c1, acc.y);
        acc.z = fmaf(h1.z, c1, acc.z); acc.w = fmaf(h1.w, c1, acc.w);
        acc.x = fmaf(h2.x, c2, acc.x); acc.y = fmaf(h2.y, c2, acc.y);
        acc.z = fmaf(h2.z, c2, acc.z); acc.w = fmaf(h2.w, c2, acc.w);
        acc.x = fmaf(h3.x, c3, acc.x); acc.y = fmaf(h3.y, c3, acc.y);
        acc.z = fmaf(h3.z, c3, acc.z); acc.w = fmaf(h3.w, c3, acc.w);
        acc.x = fmaf(h4.x, c4, acc.x); acc.y = fmaf(h4.y, c4, acc.y);
        acc.z = fmaf(h4.z, c4, acc.z); acc.w = fmaf(h4.w, c4, acc.w);
        acc.x = fmaf(h5.x, c5, acc.x); acc.y = fmaf(h5.y, c5, acc.y);
        acc.z = fmaf(h5.z, c5, acc.z); acc.w = fmaf(h5.w, c5, acc.w);
        acc.x = fmaf(h6.x, c6, acc.x); acc.y = fmaf(h6.y, c6, acc.y);
        acc.z = fmaf(h6.z, c6, acc.z); acc.w = fmaf(h6.w, c6, acc.w);
        acc.x = fmaf(h7.x, c7, acc.x); acc.y = fmaf(h7.y, c7, acc.y);
        acc.z = fmaf(h7.z, c7, acc.z); acc.w = fmaf(h7.w, c7, acc.w);
    }
    for (; t + 4 <= end; t += 4) {
        const int4 sv = *reinterpret_cast<const int4*>(&ent_d[t]);

        const float4 h0 = *reinterpret_cast<const float4*>(&H[(size_t)sv.x * 128 + ll * 4]);
        const float4 h1 = *reinterpret_cast<const float4*>(&H[(size_t)sv.y * 128 + ll * 4]);
        const float4 h2 = *reinterpret_cast<const float4*>(&H[(size_t)sv.z * 128 + ll * 4]);
        const float4 h3 = *reinterpret_cast<const float4*>(&H[(size_t)sv.w * 128 + ll * 4]);

        const float4 p0 = pk[(size_t)sv.x * 4 + h];
        const float4 p1 = pk[(size_t)sv.y * 4 + h];
        const float4 p2 = pk[(size_t)sv.z * 4 + h];
        const float4 p3 = pk[(size_t)sv.w * 4 + h];

        const float c0 = __expf(LRELU_ATT(aih + p0.x) - p0.y) * p0.z;
        const float c1 = __expf(LRELU_ATT(aih + p1.x) - p1.y) * p1.z;
        const float c2 = __expf(LRELU_ATT(aih + p2.x) - p2.y) * p2.z;
        const float c3 = __expf(LRELU_ATT(aih + p3.x) - p3.y) * p3.z;

        acc.x = fmaf(h0.x, c0, acc.x); acc.y = fmaf(h0.y, c0, acc.y);
        acc.z = fmaf(h0.z, c0, acc.z); acc.w = fmaf(h0.w, c0, acc.w);
        acc.x = fmaf(h1.x, c1, acc.x); acc.y = fmaf(h1.y, c1, acc.y);
        acc.z = fmaf(h1.z, c1, acc.z); acc.w = fmaf(h1.w, c1, acc.w);
        acc.x = fmaf(h2.x, c2, acc.x); acc.y = fmaf(h2.y, c2, acc.y);
        acc.z = fmaf(h2.z, c2, acc.z); acc.w = fmaf(h2.w, c2, acc.w);
        acc.x = fmaf(h3.x, c3, acc.x); acc.y = fmaf(h3.y, c3, acc.y);
        acc.z = fmaf(h3.z, c3, acc.z); acc.w = fmaf(h3.w, c3, acc.w);
    }
    for (; t < end; ++t) {
        const int s = ent_d[t];
        const float4 hv = *reinterpret_cast<const float4*>(&H[(size_t)s * 128 + ll * 4]);
        const float4 pv = pk[(size_t)s * 4 + h];
        const float c   = __expf(LRELU_ATT(aih + pv.x) - pv.y) * pv.z;
        acc.x = fmaf(hv.x, c, acc.x); acc.y = fmaf(hv.y, c, acc.y);
        acc.z = fmaf(hv.z, c, acc.z); acc.w = fmaf(hv.w, c, acc.w);
    }
    const float4 bv = *reinterpret_cast<const float4*>(&bias[ll * 4]);
    float4 o;
    o.x = fmaxf(acc.x + bv.x, 0.f);
    o.y = fmaxf(acc.y + bv.y, 0.f);
    o.z = fmaxf(acc.z + bv.z, 0.f);
    o.w = fmaxf(acc.w + bv.w, 0.f);
    *reinterpret_cast<float4*>(&OUT[(size_t)n * 128 + ll * 4]) = o;
}

// ---------------- output head ----------------
__global__ __launch_bounds__(256)
void out_kernel(const float* __restrict__ G, const float* __restrict__ oW,
                float* __restrict__ out3, float* __restrict__ ypredF, int N)
{
    __shared__ float w[384];
    for (int i = threadIdx.x; i < 384; i += 256) w[i] = oW[i];
    __syncthreads();
    const int n = blockIdx.x * 256 + threadIdx.x;
    if (n >= N) return;
    const float* g = G + (size_t)n * 128;
    float a0 = 0.f, a1 = 0.f, a2 = 0.f;
    for (int k = 0; k < 128; k += 4) {
        float4 gv = *reinterpret_cast<const float4*>(&g[k]);
        a0 = fmaf(gv.x, w[(k+0)*3+0], a0); a1 = fmaf(gv.x, w[(k+0)*3+1], a1); a2 = fmaf(gv.x, w[(k+0)*3+2], a2);
        a0 = fmaf(gv.y, w[(k+1)*3+0], a0); a1 = fmaf(gv.y, w[(k+1)*3+1], a1); a2 = fmaf(gv.y, w[(k+1)*3+2], a2);
        a0 = fmaf(gv.z, w[(k+2)*3+0], a0); a1 = fmaf(gv.z, w[(k+2)*3+1], a1); a2 = fmaf(gv.z, w[(k+2)*3+2], a2);
        a0 = fmaf(gv.w, w[(k+3)*3+0], a0); a1 = fmaf(gv.w, w[(k+3)*3+1], a1); a2 = fmaf(gv.w, w[(k+3)*3+2], a2);
    }
    out3[(size_t)n * 3 + 0] = a0;
    out3[(size_t)n * 3 + 1] = a1;
    out3[(size_t)n * 3 + 2] = a2;
    int idx = 0; float best = a0;
    if (a1 > best) { best = a1; idx = 1; }
    if (a2 > best) { best = a2; idx = 2; }
    ypredF[n] = (float)idx;
}

__global__ __launch_bounds__(256)
void gather_kernel(const int* __restrict__ nix, const float* __restrict__ out3,
                   const float* __restrict__ ypredF, float* __restrict__ nodeOut,
                   float* __restrict__ ynode, int M)
{
    const int i = blockIdx.x * 256 + threadIdx.x;
    if (i >= M) return;
    const int n = nix[i];
    nodeOut[(size_t)i * 3 + 0] = out3[(size_t)n * 3 + 0];
    nodeOut[(size_t)i * 3 + 1] = out3[(size_t)n * 3 + 1];
    nodeOut[(size_t)i * 3 + 2] = out3[(size_t)n * 3 + 2];
    ynode[i] = ypredF[n];
}

extern "C" void kernel_launch(void* const* d_in, const int* in_sizes, int n_in,
                              void* d_out, int out_size, void* d_ws, size_t ws_size,
                              hipStream_t stream)
{
    const float* x      = (const float*)d_in[0];
    const int*   ei     = (const int*)d_in[1];
    const int*   nodeix = (const int*)d_in[2];
    const float* phW    = (const float*)d_in[3];
    const float* phb    = (const float*)d_in[4];
    const float* Wl[3]   = {(const float*)d_in[5],  (const float*)d_in[9],  (const float*)d_in[13]};
    const float* bl[3]   = {(const float*)d_in[6],  (const float*)d_in[10], (const float*)d_in[14]};
    const float* attl[3] = {(const float*)d_in[7],  (const float*)d_in[11], (const float*)d_in[15]};
    const float* bsl[3]  = {(const float*)d_in[8],  (const float*)d_in[12], (const float*)d_in[16]};
    const float* outW    = (const float*)d_in[17];

    const int N  = in_sizes[0] / 256;
    const int E  = in_sizes[1] / 2;
    const int M  = in_sizes[2];
    const int EN = E + N;
    const int NB  = (N + 255) >> 8;         // 256-node buckets (<=512 for N<=131072)
    const int NB4 = (NB + 3) & ~3;          // padded so ent_* stay 16B-aligned

    // ---- workspace layout ----
    float*  P     = (float*)d_ws;                     // N*128
    float*  Q     = P + (size_t)N * 128;              // N*128 (aliased as CSR staging)
    float*  ai    = Q + (size_t)N * 128;              // N*4
    float4* pk    = (float4*)(ai + (size_t)N * 4);    // N*4 float4 {aj, amax, rden, -}
    float*  out3  = (float*)(pk + (size_t)N * 4);     // N*3 (pad to N*4 for alignment)
    int* row_s   = (int*)(out3 + (size_t)N * 4);      // N
    int* row_d   = row_s + N;                         // N
    int* cnt_s   = row_d + N;                         // N (degree histogram)
    int* cnt_d   = cnt_s + N;                         // N
    int* tail_s  = cnt_d + N;                         // NB4 (bucket tails, padded)
    int* tail_d  = tail_s + NB4;                      // NB4
    int* bsum_s  = tail_d + NB4;                      // 1024
    int* bsum_d  = bsum_s + 1024;                     // 1024
    int* ent_s   = bsum_d + 1024;                     // EN (16B-aligned for N%4==0)
    int* ent_d   = ent_s + (size_t)EN;                // EN

    // staging buffers alias Q (unused until the first GEMM): 2*EN ints <= N*128 floats
    int* bufA_s = (int*)Q;
    int* bufA_d = bufA_s + (size_t)EN;

    // ---- d_out layout: x_embed[N*128] node_output[M*3] ypred[N] y_nodepred[M]
    float* o_embed   = (float*)d_out;
    float* o_nodeout = o_embed + (size_t)N * 128;
    float* o_ypred   = o_nodeout + (size_t)M * 3;
    float* o_ynode   = o_ypred + N;

    const int nb = (N + 255) / 256;
    const int ng = (N + 127) / 128;   // GEMM grid

    // ---- CSR build (once; reused by all 3 layers) ----
    hipMemsetAsync(cnt_s, 0, (size_t)2 * N * sizeof(int), stream);
    count_deg<<<(EN + 255) / 256, 256, 0, stream>>>(ei, E, N, cnt_s, cnt_d);
    scan_part2<<<dim3(nb, 2), 256, 0, stream>>>(cnt_s, cnt_d, bsum_s, bsum_d, N);
    scan_bsums2<<<dim3(1, 2), 1024, 0, stream>>>(bsum_s, bsum_d, nb);
    scan_final2<<<dim3(nb, 2), 256, 0, stream>>>(cnt_s, cnt_d, bsum_s, bsum_d,
                                                 row_s, row_d, tail_s, tail_d, N);
    radix_scatter<<<(EN + SCAT_CHUNK - 1) / SCAT_CHUNK, 256, 0, stream>>>(
        ei, E, N, NB, tail_s, tail_d, bufA_s, bufA_d);
    bucket_place<<<dim3(NB, 2), 256, 0, stream>>>(row_s, ent_s, bufA_s,
                                                  row_d, ent_d, bufA_d, N, NB, EN);
    sort_rows_wave2<<<dim3((N + 3) / 4, 2), 256, 0, stream>>>(row_s, ent_s, row_d, ent_d, N, EN);

    // ---- pheno transform: P = x @ phW + phb ----
    gemm_tile<256, false><<<ng, 256, 0, stream>>>(x, phW, phb, P, nullptr, nullptr, nullptr, N);

    // ---- 3 GAT layers ----
    for (int l = 0; l < 3; ++l) {
        float* tgt = (l == 2) ? o_embed : P;   // layer 3 writes x_embed directly
        gemm_tile<128, true><<<ng, 256, 0, stream>>>(P, Wl[l], bl[l], Q, attl[l], ai, pk, N);
        softmax_src<<<(N + 3) / 4, 256, 0, stream>>>(row_s, ent_s, ai, pk, N, EN);
        aggregate_dst<<<(N + 7) / 8, 256, 0, stream>>>(row_d, ent_d, ai, pk,
                                                       Q, bsl[l], tgt, N, EN);
    }

    out_kernel<<<(N + 255) / 256, 256, 0, stream>>>(o_embed, outW, out3, o_ypred, N);
    gather_kernel<<<(M + 255) / 256, 256, 0, stream>>>(nodeix, out3, o_ypred, o_nodeout, o_ynode, M);
}